// Round 3
// baseline (741.152 us; speedup 1.0000x reference)
//
#include <hip/hip_runtime.h>

#define TB 128      // T
#define BB 8        // B
#define MM 8        // instruments
#define KP 16       // keypoints per instrument
#define KR 17       // K + root
#define NN 136      // M*KR
#define EMB 64
#define HID 128
#define G4 512      // 4*HID
#define BN 1088     // B*N
#define NEG_SLOPE 0.2f

typedef _Float16 h4 __attribute__((ext_vector_type(4)));
typedef float    f4v __attribute__((ext_vector_type(4)));

__device__ __forceinline__ float sigf(float x) { return 1.0f/(1.0f + __expf(-x)); }
__device__ __forceinline__ float tanhf_fast(float x) {
  x = fminf(fmaxf(x, -15.0f), 15.0f);
  float e = __expf(2.0f*x);
  return (e - 1.0f)/(e + 1.0f);
}
// barrier that drains only LDS (lgkm), NOT global stores (vmcnt) — all
// cross-wave data in k2 flows through LDS; global r-stores are fire-and-forget.
__device__ __forceinline__ void bar_lds() {
  asm volatile("s_waitcnt lgkmcnt(0)\n\ts_barrier" ::: "memory");
}

// ---------------------------------------------------------------------------
// K1: root synthesis + 2-layer MLP -> x[t][b*NN+n][e]  (one block per (b,t))
// ---------------------------------------------------------------------------
__global__ __launch_bounds__(256) void k1_mlp(
    const float* __restrict__ feat, const float* __restrict__ W1,
    const float* __restrict__ b1, const float* __restrict__ W2,
    const float* __restrict__ b2, float* __restrict__ x)
{
  __shared__ float fl[MM*KP*3];
  __shared__ float fR[NN][3];
  __shared__ float hidl[NN][EMB];
  const int bt = blockIdx.x;
  const int b = bt >> 7;          // bt / T  (T == 128)
  const int t = bt & 127;
  const int tid = threadIdx.x;

  const float* fp = feat + (size_t)bt * (MM*KP*3);
  for (int i = tid; i < MM*KP*3; i += 256) fl[i] = fp[i];
  __syncthreads();

  if (tid < NN) {
    int n = tid, m = n / KR, kk = n - m*KR;
    if (kk < KP) {
      fR[n][0] = fl[(m*KP+kk)*3+0];
      fR[n][1] = fl[(m*KP+kk)*3+1];
      fR[n][2] = fl[(m*KP+kk)*3+2];
    } else {
      float sx = 0.f, sy = 0.f, sw = 0.f;
      for (int k = 0; k < KP; ++k) {
        float vz = fl[(m*KP+k)*3+2];
        float w = (vz > 0.5f) ? 1.0f : 0.0f;
        sx += fl[(m*KP+k)*3+0]*w;
        sy += fl[(m*KP+k)*3+1]*w;
        sw += w;
      }
      float dn = fmaxf(sw, 1.0f);
      fR[n][0] = sx/dn; fR[n][1] = sy/dn; fR[n][2] = (sw > 0.f) ? 1.f : 0.f;
    }
  }
  __syncthreads();

  const int p = tid & 31, e0 = p*2, nb = tid >> 5;   // 8 row-groups of 17
  float w10a = W1[e0],   w11a = W1[EMB+e0],   w12a = W1[2*EMB+e0],   b1a = b1[e0];
  float w10b = W1[e0+1], w11b = W1[EMB+e0+1], w12b = W1[2*EMB+e0+1], b1b = b1[e0+1];
  for (int ni = 0; ni < 17; ++ni) {
    int n = nb*17 + ni;
    float xx = fR[n][0], yy = fR[n][1], zz = fR[n][2];
    float va = fmaf(xx,w10a, fmaf(yy,w11a, fmaf(zz,w12a, b1a)));
    float vb = fmaf(xx,w10b, fmaf(yy,w11b, fmaf(zz,w12b, b1b)));
    *(float2*)&hidl[n][e0] = make_float2(fmaxf(va,0.f), fmaxf(vb,0.f));
  }
  float2 w2c[EMB];
  #pragma unroll
  for (int j = 0; j < EMB; ++j) w2c[j] = *(const float2*)&W2[(size_t)j*EMB + e0];
  float b2a = b2[e0], b2b = b2[e0+1];
  __syncthreads();

  float* xo = x + ((size_t)t*BN + (size_t)b*NN)*EMB + e0;
  for (int ni = 0; ni < 17; ++ni) {
    int n = nb*17 + ni;
    float aa = b2a, ab = b2b;
    const float4* h4p = (const float4*)hidl[n];
    #pragma unroll
    for (int j4 = 0; j4 < 16; ++j4) {
      float4 hv = h4p[j4];
      aa = fmaf(hv.x, w2c[4*j4+0].x, aa); ab = fmaf(hv.x, w2c[4*j4+0].y, ab);
      aa = fmaf(hv.y, w2c[4*j4+1].x, aa); ab = fmaf(hv.y, w2c[4*j4+1].y, ab);
      aa = fmaf(hv.z, w2c[4*j4+2].x, aa); ab = fmaf(hv.z, w2c[4*j4+2].y, ab);
      aa = fmaf(hv.w, w2c[4*j4+3].x, aa); ab = fmaf(hv.w, w2c[4*j4+3].y, ab);
    }
    *(float2*)&xo[(size_t)n*EMB] = make_float2(aa, ab);
  }
}

// ---------------------------------------------------------------------------
// K2: LSTM on the MATRIX pipe. 68 blocks x 512 threads (8 waves), 16 seqs/blk.
// Per step: z = W_f16 @ (v_hi + v_lo), v = [x;h] split-f16, fp32 MFMA accum
// (residual error = W f16-rounding only, ~1e-4/step).
// Wave w owns gate-rows [64w,64w+64) = 4 Mtiles of 16; full K=192 = 12 ktiles
// pinned as f16 A-frags (96 VGPR). B-frags are BUILT in fragment order in LDS
// (blds[kt][lane] = 16B {hi4|lo4}) by the gate/x threads, so loading B is a
// plain ds_read per ktile — no transpose reads.
// MFMA C (z, bias pre-added via C-init) -> zlds -> gate threads read their
// (i,f,g,o) quads as 4x b128, update c/h in fp32, write h-frags for t+1,
// store r as float4 (fire-and-forget; lgkm-only barriers as before).
//   frag maps (v_mfma_f32_16x16x16f16):
//     A: lane l -> A[row=l&15][k=4*(l>>4)+e]   B: lane l -> B[k=4*(l>>4)+e][col=l&15]
//     C: lane l, reg q -> D[row=4*(l>>4)+q][col=l&15]
//   element (k,s) lives at blds[k>>4][s + 16*((k>>2)&3)] elem (k&3).
// ---------------------------------------------------------------------------
__global__ __launch_bounds__(512, 2) void k2_lstm(
    const float* __restrict__ x, const float* __restrict__ W_ih,
    const float* __restrict__ W_hh, const float* __restrict__ b_ih,
    const float* __restrict__ b_hh, float* __restrict__ r)
{
  __shared__ h4  blds[12*64*2];     // [kt][lane][{hi,lo}]  12 KB
  __shared__ f4v zlds[32*64];       // [g16][lane] -> 4 z-rows/lane  32 KB
  const int tid = threadIdx.x;
  const int w   = tid >> 6;         // wave 0..7
  const int l   = tid & 63;
  const int lr  = l & 15;           // frag row/col
  const int lg  = l >> 4;           // k-subgroup
  const int s0  = blockIdx.x * 16;

  // ---- A-frags: W as f16, rows 64w..64w+63, all K ----
  h4 A[4][12];
  #pragma unroll
  for (int m = 0; m < 4; ++m) {
    int row = 64*w + 16*m + lr;
    const float* wih = W_ih + (size_t)row*64;
    const float* whh = W_hh + (size_t)row*128;
    #pragma unroll
    for (int kt = 0; kt < 12; ++kt) {
      int k = kt*16 + lg*4;
      float4 wv = (k < 64) ? *(const float4*)(wih + k)
                           : *(const float4*)(whh + (k - 64));
      A[m][kt] = h4{(_Float16)wv.x,(_Float16)wv.y,(_Float16)wv.z,(_Float16)wv.w};
    }
  }
  #pragma unroll
  for (int m = 0; m < 4; ++m)
    #pragma unroll
    for (int kt = 0; kt < 12; ++kt)
      asm volatile("" : "+v"(A[m][kt]));

  // per-wave bias in C layout (pre-added via C-init each step)
  f4v biasC[4];
  #pragma unroll
  for (int m = 0; m < 4; ++m)
    #pragma unroll
    for (int q = 0; q < 4; ++q) {
      int row = 64*w + 16*m + lg*4 + q;
      biasC[m][q] = b_ih[row] + b_hh[row];
    }

  // gate-thread coords: (seq sg, hidden j0..j0+3)
  const int sg = tid >> 5;
  const int j0 = (tid & 31) * 4;
  const int laneh = sg + 16*((j0 >> 2) & 3);
  const int hoff  = ((4 + (j0 >> 4))*64 + laneh) * 2;   // h4 index in blds
  const int zi4   = (j0 >> 4)*64 + laneh;               // f4v index (+G*512)

  // x-writer coords (tid < 256): (seq sx, k-quad kq)
  const int sx = tid >> 4;
  const int kq = (tid & 15) * 4;
  const int xoff = ((kq >> 4)*64 + (sx + 16*((kq >> 2) & 3))) * 2;

  // r-store base
  const int qq = s0 + sg;
  const int b  = qq / NN, n = qq - b*NN;
  float* rp0 = r + (((size_t)b*TB)*NN + n)*HID + j0;
  const size_t rstep = (size_t)NN*HID;

  // init: zero h-frag region (kt>=4), stage x(t=0) frags
  for (int i = 512 + tid; i < 1536; i += 512)
    blds[i] = h4{(_Float16)0.f,(_Float16)0.f,(_Float16)0.f,(_Float16)0.f};
  if (tid < 256) {
    float4 xv = *(const float4*)(x + ((size_t)(s0 + sx))*EMB + kq);
    h4 xh = h4{(_Float16)xv.x,(_Float16)xv.y,(_Float16)xv.z,(_Float16)xv.w};
    h4 xl = h4{(_Float16)(xv.x-(float)xh[0]),(_Float16)(xv.y-(float)xh[1]),
               (_Float16)(xv.z-(float)xh[2]),(_Float16)(xv.w-(float)xh[3])};
    blds[xoff] = xh; blds[xoff+1] = xl;
  }
  __syncthreads();

  float c0=0.f, c1=0.f, c2=0.f, c3=0.f;

  for (int t = 0; t < TB; ++t) {
    // prefetch x(t+1) FIRST (oldest vmem entry; published at end of phase 2)
    float4 xpre = make_float4(0.f,0.f,0.f,0.f);
    if (tid < 256) {
      int tp = (t+1 < TB) ? t+1 : t;
      xpre = *(const float4*)(x + ((size_t)tp*BN + s0 + sx)*EMB + kq);
    }

    // ---- phase 1: MFMA z = W@(v_hi) + W@(v_lo), bias pre-added ----
    h4 Bh[12], Bl[12];
    #pragma unroll
    for (int kt = 0; kt < 12; ++kt) {
      Bh[kt] = blds[(kt*64 + l)*2];
      Bl[kt] = blds[(kt*64 + l)*2 + 1];
    }
    f4v C[4] = {biasC[0], biasC[1], biasC[2], biasC[3]};
    #pragma unroll
    for (int kt = 0; kt < 12; ++kt) {
      #pragma unroll
      for (int m = 0; m < 4; ++m)
        C[m] = __builtin_amdgcn_mfma_f32_16x16x16f16(A[m][kt], Bh[kt], C[m], 0, 0, 0);
      #pragma unroll
      for (int m = 0; m < 4; ++m)
        C[m] = __builtin_amdgcn_mfma_f32_16x16x16f16(A[m][kt], Bl[kt], C[m], 0, 0, 0);
    }
    #pragma unroll
    for (int m = 0; m < 4; ++m) zlds[(4*w + m)*64 + l] = C[m];
    bar_lds();

    // ---- phase 2: gates + h + r-store + B(t+1) frags ----
    f4v zi = zlds[       zi4];
    f4v zf = zlds[ 512 + zi4];
    f4v zg = zlds[1024 + zi4];
    f4v zo = zlds[1536 + zi4];
    float h0,h1,h2,h3;
    { float cc = sigf(zf[0])*c0 + sigf(zi[0])*tanhf_fast(zg[0]); h0 = sigf(zo[0])*tanhf_fast(cc); c0 = cc; }
    { float cc = sigf(zf[1])*c1 + sigf(zi[1])*tanhf_fast(zg[1]); h1 = sigf(zo[1])*tanhf_fast(cc); c1 = cc; }
    { float cc = sigf(zf[2])*c2 + sigf(zi[2])*tanhf_fast(zg[2]); h2 = sigf(zo[2])*tanhf_fast(cc); c2 = cc; }
    { float cc = sigf(zf[3])*c3 + sigf(zi[3])*tanhf_fast(zg[3]); h3 = sigf(zo[3])*tanhf_fast(cc); c3 = cc; }
    *(float4*)(rp0 + (size_t)t*rstep) = make_float4(h0,h1,h2,h3);   // fire-and-forget
    h4 hh = h4{(_Float16)h0,(_Float16)h1,(_Float16)h2,(_Float16)h3};
    h4 hl = h4{(_Float16)(h0-(float)hh[0]),(_Float16)(h1-(float)hh[1]),
               (_Float16)(h2-(float)hh[2]),(_Float16)(h3-(float)hh[3])};
    blds[hoff]   = hh;
    blds[hoff+1] = hl;
    if (tid < 256) {   // publish prefetched x(t+1) frags (vmcnt wait covers x only)
      h4 xh = h4{(_Float16)xpre.x,(_Float16)xpre.y,(_Float16)xpre.z,(_Float16)xpre.w};
      h4 xl = h4{(_Float16)(xpre.x-(float)xh[0]),(_Float16)(xpre.y-(float)xh[1]),
                 (_Float16)(xpre.z-(float)xh[2]),(_Float16)(xpre.w-(float)xh[3])};
      blds[xoff] = xh; blds[xoff+1] = xl;
    }
    bar_lds();
  }
}

// ---------------------------------------------------------------------------
// K3: GAT. s = r@(Wg@a) matvecs; agg in r-space; ONE 16x128x128 GEMM
// H2=[r_roots;aggR]@Wg with coalesced Wg loads and broadcast V^T from LDS.
// ---------------------------------------------------------------------------
__global__ __launch_bounds__(256) void k3_gat(
    const float* __restrict__ r, const float* __restrict__ Wg,
    const float* __restrict__ a_src, const float* __restrict__ a_dst,
    float* __restrict__ rhat)
{
  __shared__ float rl[NN*132];          // r rows padded to 132 floats (71.8 KB)
  __shared__ float waS[HID], waD[HID];
  __shared__ float ssrc[NN], sdst[NN];
  __shared__ float alpha[MM][24];
  __shared__ float aggR[MM][HID];
  __shared__ float v16[HID*20];         // V^T [k][row], row-pad 20 (16B-aligned)
  __shared__ float h2[16][HID];
  const int bt = blockIdx.x;
  const int tid = threadIdx.x;
  const float* rb = r + (size_t)bt*NN*HID;

  // stage r
  {
    const float4* rb4 = (const float4*)rb;
    for (int i = tid; i < NN*32; i += 256) {
      int n = i >> 5, k4 = i & 31;
      *(float4*)&rl[n*132 + k4*4] = rb4[i];
    }
  }
  // wa = Wg @ a  (two 128-dot columns over 256 threads)
  {
    int half = tid >> 7, j = tid & 127;
    const float* av = half ? a_dst : a_src;
    float acc = 0.f;
    for (int k = 0; k < HID; ++k) acc = fmaf(Wg[(size_t)k*HID + j], av[k], acc);
    if (half) waD[j] = acc; else waS[j] = acc;
  }
  __syncthreads();
  // scores
  for (int job = tid; job < 2*NN; job += 256) {
    int n = job >> 1, which = job & 1;
    const float4* rn = (const float4*)&rl[n*132];
    const float4* wa = (const float4*)(which ? waD : waS);
    float acc = 0.f;
    #pragma unroll
    for (int i = 0; i < 32; ++i) {
      float4 a4 = rn[i], b4 = wa[i];
      acc = fmaf(a4.x,b4.x, fmaf(a4.y,b4.y, fmaf(a4.z,b4.z, fmaf(a4.w,b4.w, acc))));
    }
    if (which) sdst[n] = acc; else ssrc[n] = acc;
  }
  __syncthreads();
  // softmax over each root's 23 incoming edges
  if (tid < MM) {
    int m = tid;
    float sd = sdst[m*KR + KP];
    float ev[23]; float mx = -1e30f;
    #pragma unroll
    for (int k = 0; k < 23; ++k) {
      int srcn;
      if (k < KP) srcn = m*KR + k;
      else { int rr = k - KP; rr += (rr >= m) ? 1 : 0; srcn = rr*KR + KP; }
      float e = ssrc[srcn] + sd;
      e = (e > 0.f) ? e : NEG_SLOPE*e;
      ev[k] = e; mx = fmaxf(mx, e);
    }
    float den = 0.f;
    #pragma unroll
    for (int k = 0; k < 23; ++k) { float ex = __expf(ev[k]-mx); ev[k] = ex; den += ex; }
    float inv = 1.f/den;
    #pragma unroll
    for (int k = 0; k < 23; ++k) alpha[m][k] = ev[k]*inv;
  }
  __syncthreads();
  // aggregate in r-space
  {
    int m = tid >> 5, jq = (tid & 31)*4;
    float4 acc = make_float4(0.f,0.f,0.f,0.f);
    #pragma unroll
    for (int k = 0; k < 23; ++k) {
      int srcn;
      if (k < KP) srcn = m*KR + k;
      else { int rr = k - KP; rr += (rr >= m) ? 1 : 0; srcn = rr*KR + KP; }
      float al = alpha[m][k];
      float4 hv = *(const float4*)&rl[srcn*132 + jq];
      acc.x = fmaf(al, hv.x, acc.x); acc.y = fmaf(al, hv.y, acc.y);
      acc.z = fmaf(al, hv.z, acc.z); acc.w = fmaf(al, hv.w, acc.w);
    }
    *(float4*)&aggR[m][jq] = acc;
  }
  __syncthreads();
  // build V^T: v16[k][row] = (row<8 ? r_root[row][k] : aggR[row-8][k])
  for (int idx = tid; idx < 16*HID; idx += 256) {
    int k = idx & 127, row = idx >> 7;
    float v = (row < 8) ? rl[(row*KR + KP)*132 + k] : aggR[row-8][k];
    v16[k*20 + row] = v;
  }
  __syncthreads();
  // H2 = V(16x128) @ Wg(128x128): thread = (row-half, col j).
  // Wg: one coalesced b32/iter (L2-hot); V^T: all-lane-broadcast float4s.
  {
    int half = tid >> 7, j = tid & 127;
    float acc[8] = {0.f,0.f,0.f,0.f,0.f,0.f,0.f,0.f};
    const float* wgp = Wg + j;
    #pragma unroll 4
    for (int k = 0; k < HID; ++k) {
      float wv = wgp[(size_t)k*HID];
      const float4* vv = (const float4*)&v16[k*20 + half*8];
      float4 va = vv[0], vb = vv[1];
      acc[0] = fmaf(va.x, wv, acc[0]); acc[1] = fmaf(va.y, wv, acc[1]);
      acc[2] = fmaf(va.z, wv, acc[2]); acc[3] = fmaf(va.w, wv, acc[3]);
      acc[4] = fmaf(vb.x, wv, acc[4]); acc[5] = fmaf(vb.y, wv, acc[5]);
      acc[6] = fmaf(vb.z, wv, acc[6]); acc[7] = fmaf(vb.w, wv, acc[7]);
    }
    #pragma unroll
    for (int q = 0; q < 8; ++q) h2[half*8 + q][j] = acc[q];
  }
  __syncthreads();
  // output: leaves elu(H2[m]); roots elu(H2[8+m]); coalesced over j
  {
    int j = tid & 127, half = tid >> 7;
    float* out = rhat + (size_t)bt*NN*HID + j;
    for (int ni = 0; ni < 68; ++ni) {
      int n = half*68 + ni;
      int m = n / KR, kk = n - m*KR;
      float v = (kk < KP) ? h2[m][j] : h2[8+m][j];
      v = (v > 0.f) ? v : (__expf(v) - 1.f);
      out[(size_t)n*HID] = v;
    }
  }
}

// ---------------------------------------------------------------------------
extern "C" void kernel_launch(void* const* d_in, const int* in_sizes, int n_in,
                              void* d_out, int out_size, void* d_ws, size_t ws_size,
                              hipStream_t stream) {
  (void)in_sizes; (void)n_in; (void)out_size; (void)ws_size;
  const float* feat  = (const float*)d_in[0];
  const float* W1    = (const float*)d_in[1];
  const float* b1    = (const float*)d_in[2];
  const float* W2    = (const float*)d_in[3];
  const float* b2    = (const float*)d_in[4];
  const float* W_ih  = (const float*)d_in[5];
  const float* W_hh  = (const float*)d_in[6];
  const float* b_ih  = (const float*)d_in[7];
  const float* b_hh  = (const float*)d_in[8];
  const float* Wg    = (const float*)d_in[9];
  const float* a_src = (const float*)d_in[10];
  const float* a_dst = (const float*)d_in[11];

  float* x    = (float*)d_ws;                       // (T, B*N, EMB) fp32 = 35.7 MB
  float* r    = (float*)d_out;                      // (B, T, N, HID)
  float* rhat = r + (size_t)BB*TB*NN*HID;           // (B, T, N, HID)

  k1_mlp<<<BB*TB, 256, 0, stream>>>(feat, W1, b1, W2, b2, x);
  k2_lstm<<<68, 512, 0, stream>>>(x, W_ih, W_hh, b_ih, b_hh, r);
  k3_gat<<<BB*TB, 256, 0, stream>>>(r, Wg, a_src, a_dst, rhat);
}

// Round 4
// 676.855 us; speedup vs baseline: 1.0950x; 1.0950x over previous
//
#include <hip/hip_runtime.h>

#define TB 128      // T
#define BB 8        // B
#define MM 8        // instruments
#define KP 16       // keypoints per instrument
#define KR 17       // K + root
#define NN 136      // M*KR
#define EMB 64
#define HID 128
#define G4 512      // 4*HID
#define BN 1088     // B*N
#define NEG_SLOPE 0.2f

typedef _Float16 h4 __attribute__((ext_vector_type(4)));
typedef float    f4v __attribute__((ext_vector_type(4)));

__device__ __forceinline__ float sigf(float x) { return 1.0f/(1.0f + __expf(-x)); }
__device__ __forceinline__ float tanhf_fast(float x) {
  x = fminf(fmaxf(x, -15.0f), 15.0f);
  float e = __expf(2.0f*x);
  return (e - 1.0f)/(e + 1.0f);
}
// barrier that drains only LDS (lgkm), NOT global stores (vmcnt) — all
// cross-wave data in k2 flows through LDS; global r-stores are fire-and-forget.
__device__ __forceinline__ void bar_lds() {
  asm volatile("s_waitcnt lgkmcnt(0)\n\ts_barrier" ::: "memory");
}

// ---------------------------------------------------------------------------
// K1: root synthesis + 2-layer MLP -> x[t][b*NN+n][e]  (one block per (b,t))
// ---------------------------------------------------------------------------
__global__ __launch_bounds__(256) void k1_mlp(
    const float* __restrict__ feat, const float* __restrict__ W1,
    const float* __restrict__ b1, const float* __restrict__ W2,
    const float* __restrict__ b2, float* __restrict__ x)
{
  __shared__ float fl[MM*KP*3];
  __shared__ float fR[NN][3];
  __shared__ float hidl[NN][EMB];
  const int bt = blockIdx.x;
  const int b = bt >> 7;          // bt / T  (T == 128)
  const int t = bt & 127;
  const int tid = threadIdx.x;

  const float* fp = feat + (size_t)bt * (MM*KP*3);
  for (int i = tid; i < MM*KP*3; i += 256) fl[i] = fp[i];
  __syncthreads();

  if (tid < NN) {
    int n = tid, m = n / KR, kk = n - m*KR;
    if (kk < KP) {
      fR[n][0] = fl[(m*KP+kk)*3+0];
      fR[n][1] = fl[(m*KP+kk)*3+1];
      fR[n][2] = fl[(m*KP+kk)*3+2];
    } else {
      float sx = 0.f, sy = 0.f, sw = 0.f;
      for (int k = 0; k < KP; ++k) {
        float vz = fl[(m*KP+k)*3+2];
        float w = (vz > 0.5f) ? 1.0f : 0.0f;
        sx += fl[(m*KP+k)*3+0]*w;
        sy += fl[(m*KP+k)*3+1]*w;
        sw += w;
      }
      float dn = fmaxf(sw, 1.0f);
      fR[n][0] = sx/dn; fR[n][1] = sy/dn; fR[n][2] = (sw > 0.f) ? 1.f : 0.f;
    }
  }
  __syncthreads();

  const int p = tid & 31, e0 = p*2, nb = tid >> 5;   // 8 row-groups of 17
  float w10a = W1[e0],   w11a = W1[EMB+e0],   w12a = W1[2*EMB+e0],   b1a = b1[e0];
  float w10b = W1[e0+1], w11b = W1[EMB+e0+1], w12b = W1[2*EMB+e0+1], b1b = b1[e0+1];
  for (int ni = 0; ni < 17; ++ni) {
    int n = nb*17 + ni;
    float xx = fR[n][0], yy = fR[n][1], zz = fR[n][2];
    float va = fmaf(xx,w10a, fmaf(yy,w11a, fmaf(zz,w12a, b1a)));
    float vb = fmaf(xx,w10b, fmaf(yy,w11b, fmaf(zz,w12b, b1b)));
    *(float2*)&hidl[n][e0] = make_float2(fmaxf(va,0.f), fmaxf(vb,0.f));
  }
  float2 w2c[EMB];
  #pragma unroll
  for (int j = 0; j < EMB; ++j) w2c[j] = *(const float2*)&W2[(size_t)j*EMB + e0];
  float b2a = b2[e0], b2b = b2[e0+1];
  __syncthreads();

  float* xo = x + ((size_t)t*BN + (size_t)b*NN)*EMB + e0;
  for (int ni = 0; ni < 17; ++ni) {
    int n = nb*17 + ni;
    float aa = b2a, ab = b2b;
    const float4* h4p = (const float4*)hidl[n];
    #pragma unroll
    for (int j4 = 0; j4 < 16; ++j4) {
      float4 hv = h4p[j4];
      aa = fmaf(hv.x, w2c[4*j4+0].x, aa); ab = fmaf(hv.x, w2c[4*j4+0].y, ab);
      aa = fmaf(hv.y, w2c[4*j4+1].x, aa); ab = fmaf(hv.y, w2c[4*j4+1].y, ab);
      aa = fmaf(hv.z, w2c[4*j4+2].x, aa); ab = fmaf(hv.z, w2c[4*j4+2].y, ab);
      aa = fmaf(hv.w, w2c[4*j4+3].x, aa); ab = fmaf(hv.w, w2c[4*j4+3].y, ab);
    }
    *(float2*)&xo[(size_t)n*EMB] = make_float2(aa, ab);
  }
}

// ---------------------------------------------------------------------------
// K2: LSTM on the MATRIX pipe. 68 blocks x 512 threads (8 waves), 16 seqs/blk.
// Per step: z = W_f16 @ (v_hi + v_lo), v=[x;h] split-f16, fp32 MFMA accum.
// BANK-AWARE LAYOUT (round-3 had 2.26e7 conflicts = ~2600 cyc/step):
//   * Bh/Bl are SEPARATE arrays [kt][lane] (8B elems) -> every frag read is
//     arr[kt*64+l], lane-contiguous b64, conflict-free.
//   * gate thread (wave w, lane l) owns seq=l&15, j0=16w+4*(l>>4). Then:
//       - its h-frag write lands at Bh[(4+w)*64 + l]   (contiguous b64)
//       - its z-read is zlds[(g*8+w)*64 + l], g=0..3   (contiguous b128)
//     (identity: slot = (l&15)+16*(l>>4) = l; kt = 4+w; G = g*8+w.)
//   * x-writer wave w<4 writes ktile w: Bh[w*64+l], loads x at k=16w+4*(l>>4).
//   * zlds phase-1 writes: zlds[(4w+m)*64+l], contiguous b128.
// frag maps (v_mfma_f32_16x16x16f16), pass-verified round 3:
//   A: lane l -> A[row=l&15][k=4*(l>>4)+e]  B: lane l -> B[k=4*(l>>4)+e][col=l&15]
//   C: lane l, reg q -> D[row=4*(l>>4)+q][col=l&15]
// ---------------------------------------------------------------------------
__global__ __launch_bounds__(512, 2) void k2_lstm(
    const float* __restrict__ x, const float* __restrict__ W_ih,
    const float* __restrict__ W_hh, const float* __restrict__ b_ih,
    const float* __restrict__ b_hh, float* __restrict__ r)
{
  __shared__ h4  Bh[12*64];         // v_hi frags [kt][lane]   6 KB
  __shared__ h4  Bl[12*64];         // v_lo frags [kt][lane]   6 KB
  __shared__ f4v zlds[32*64];       // z [G][lane] (4 rows/lane) 32 KB
  const int tid = threadIdx.x;
  const int w   = tid >> 6;         // wave 0..7
  const int l   = tid & 63;
  const int lr  = l & 15;           // frag row/col  (also: my seq)
  const int lg  = l >> 4;           // k-subgroup    (also: my j-quad)
  const int s0  = blockIdx.x * 16;

  // ---- A-frags: W as f16, rows 64w..64w+63, all K=192 ----
  h4 A[4][12];
  #pragma unroll
  for (int m = 0; m < 4; ++m) {
    int row = 64*w + 16*m + lr;
    const float* wih = W_ih + (size_t)row*64;
    const float* whh = W_hh + (size_t)row*128;
    #pragma unroll
    for (int kt = 0; kt < 12; ++kt) {
      int k = kt*16 + lg*4;
      float4 wv = (k < 64) ? *(const float4*)(wih + k)
                           : *(const float4*)(whh + (k - 64));
      A[m][kt] = h4{(_Float16)wv.x,(_Float16)wv.y,(_Float16)wv.z,(_Float16)wv.w};
    }
  }
  #pragma unroll
  for (int m = 0; m < 4; ++m)
    #pragma unroll
    for (int kt = 0; kt < 12; ++kt)
      asm volatile("" : "+v"(A[m][kt]));

  // per-wave bias in C layout (pre-added via C-init each step)
  f4v biasC[4];
  #pragma unroll
  for (int m = 0; m < 4; ++m)
    #pragma unroll
    for (int q = 0; q < 4; ++q) {
      int row = 64*w + 16*m + lg*4 + q;
      biasC[m][q] = b_ih[row] + b_hh[row];
    }

  // gate-thread coords: seq = lr, hidden j0..j0+3
  const int j0 = 16*w + 4*lg;

  // r-store base
  const int qq = s0 + lr;
  const int b  = qq / NN, n = qq - b*NN;
  float* rp0 = r + (((size_t)b*TB)*NN + n)*HID + j0;
  const size_t rstep = (size_t)NN*HID;

  // init: zero h-frag ktiles (4..11), stage x(t=0) frags (waves 0..3)
  {
    h4 z0 = h4{(_Float16)0.f,(_Float16)0.f,(_Float16)0.f,(_Float16)0.f};
    Bh[256 + tid] = z0; Bl[256 + tid] = z0;
    if (w < 4) {
      float4 xv = *(const float4*)(x + ((size_t)(s0 + lr))*EMB + 16*w + 4*lg);
      h4 xh = h4{(_Float16)xv.x,(_Float16)xv.y,(_Float16)xv.z,(_Float16)xv.w};
      h4 xl = h4{(_Float16)(xv.x-(float)xh[0]),(_Float16)(xv.y-(float)xh[1]),
                 (_Float16)(xv.z-(float)xh[2]),(_Float16)(xv.w-(float)xh[3])};
      Bh[w*64 + l] = xh; Bl[w*64 + l] = xl;
    }
  }
  __syncthreads();

  float c0=0.f, c1=0.f, c2=0.f, c3=0.f;

  for (int t = 0; t < TB; ++t) {
    // prefetch x(t+1) FIRST (oldest vmem entry; its wait won't drain r-stores)
    float4 xpre = make_float4(0.f,0.f,0.f,0.f);
    if (w < 4) {
      int tp = (t+1 < TB) ? t+1 : t;
      xpre = *(const float4*)(x + ((size_t)tp*BN + s0 + lr)*EMB + 16*w + 4*lg);
    }

    // ---- phase 1: z = W@v_hi + W@v_lo, bias in C-init ----
    f4v C[4] = {biasC[0], biasC[1], biasC[2], biasC[3]};
    #pragma unroll
    for (int kt = 0; kt < 12; ++kt) {
      h4 bh = Bh[kt*64 + l];
      h4 bl = Bl[kt*64 + l];
      #pragma unroll
      for (int m = 0; m < 4; ++m)
        C[m] = __builtin_amdgcn_mfma_f32_16x16x16f16(A[m][kt], bh, C[m], 0, 0, 0);
      #pragma unroll
      for (int m = 0; m < 4; ++m)
        C[m] = __builtin_amdgcn_mfma_f32_16x16x16f16(A[m][kt], bl, C[m], 0, 0, 0);
    }
    #pragma unroll
    for (int m = 0; m < 4; ++m) zlds[(4*w + m)*64 + l] = C[m];
    bar_lds();

    // ---- phase 2: gates + h + r-store + B(t+1) frags ----
    f4v zi = zlds[(0*8 + w)*64 + l];
    f4v zf = zlds[(1*8 + w)*64 + l];
    f4v zg = zlds[(2*8 + w)*64 + l];
    f4v zo = zlds[(3*8 + w)*64 + l];
    float h0,h1,h2,h3;
    { float cc = sigf(zf[0])*c0 + sigf(zi[0])*tanhf_fast(zg[0]); h0 = sigf(zo[0])*tanhf_fast(cc); c0 = cc; }
    { float cc = sigf(zf[1])*c1 + sigf(zi[1])*tanhf_fast(zg[1]); h1 = sigf(zo[1])*tanhf_fast(cc); c1 = cc; }
    { float cc = sigf(zf[2])*c2 + sigf(zi[2])*tanhf_fast(zg[2]); h2 = sigf(zo[2])*tanhf_fast(cc); c2 = cc; }
    { float cc = sigf(zf[3])*c3 + sigf(zi[3])*tanhf_fast(zg[3]); h3 = sigf(zo[3])*tanhf_fast(cc); c3 = cc; }
    *(float4*)(rp0 + (size_t)t*rstep) = make_float4(h0,h1,h2,h3);   // fire-and-forget
    h4 hh = h4{(_Float16)h0,(_Float16)h1,(_Float16)h2,(_Float16)h3};
    h4 hl = h4{(_Float16)(h0-(float)hh[0]),(_Float16)(h1-(float)hh[1]),
               (_Float16)(h2-(float)hh[2]),(_Float16)(h3-(float)hh[3])};
    Bh[(4 + w)*64 + l] = hh;
    Bl[(4 + w)*64 + l] = hl;
    if (w < 4) {   // publish prefetched x(t+1) frags
      h4 xh = h4{(_Float16)xpre.x,(_Float16)xpre.y,(_Float16)xpre.z,(_Float16)xpre.w};
      h4 xl = h4{(_Float16)(xpre.x-(float)xh[0]),(_Float16)(xpre.y-(float)xh[1]),
                 (_Float16)(xpre.z-(float)xh[2]),(_Float16)(xpre.w-(float)xh[3])};
      Bh[w*64 + l] = xh; Bl[w*64 + l] = xl;
    }
    bar_lds();
  }
}

// ---------------------------------------------------------------------------
// K3: GAT. s = r@(Wg@a) matvecs; agg in r-space; ONE 16x128x128 GEMM
// H2=[r_roots;aggR]@Wg with coalesced Wg loads and broadcast V^T from LDS.
// ---------------------------------------------------------------------------
__global__ __launch_bounds__(256) void k3_gat(
    const float* __restrict__ r, const float* __restrict__ Wg,
    const float* __restrict__ a_src, const float* __restrict__ a_dst,
    float* __restrict__ rhat)
{
  __shared__ float rl[NN*132];          // r rows padded to 132 floats (71.8 KB)
  __shared__ float waS[HID], waD[HID];
  __shared__ float ssrc[NN], sdst[NN];
  __shared__ float alpha[MM][24];
  __shared__ float aggR[MM][HID];
  __shared__ float v16[HID*20];         // V^T [k][row], row-pad 20 (16B-aligned)
  __shared__ float h2[16][HID];
  const int bt = blockIdx.x;
  const int tid = threadIdx.x;
  const float* rb = r + (size_t)bt*NN*HID;

  // stage r
  {
    const float4* rb4 = (const float4*)rb;
    for (int i = tid; i < NN*32; i += 256) {
      int n = i >> 5, k4 = i & 31;
      *(float4*)&rl[n*132 + k4*4] = rb4[i];
    }
  }
  // wa = Wg @ a  (two 128-dot columns over 256 threads)
  {
    int half = tid >> 7, j = tid & 127;
    const float* av = half ? a_dst : a_src;
    float acc = 0.f;
    for (int k = 0; k < HID; ++k) acc = fmaf(Wg[(size_t)k*HID + j], av[k], acc);
    if (half) waD[j] = acc; else waS[j] = acc;
  }
  __syncthreads();
  // scores
  for (int job = tid; job < 2*NN; job += 256) {
    int n = job >> 1, which = job & 1;
    const float4* rn = (const float4*)&rl[n*132];
    const float4* wa = (const float4*)(which ? waD : waS);
    float acc = 0.f;
    #pragma unroll
    for (int i = 0; i < 32; ++i) {
      float4 a4 = rn[i], b4 = wa[i];
      acc = fmaf(a4.x,b4.x, fmaf(a4.y,b4.y, fmaf(a4.z,b4.z, fmaf(a4.w,b4.w, acc))));
    }
    if (which) sdst[n] = acc; else ssrc[n] = acc;
  }
  __syncthreads();
  // softmax over each root's 23 incoming edges
  if (tid < MM) {
    int m = tid;
    float sd = sdst[m*KR + KP];
    float ev[23]; float mx = -1e30f;
    #pragma unroll
    for (int k = 0; k < 23; ++k) {
      int srcn;
      if (k < KP) srcn = m*KR + k;
      else { int rr = k - KP; rr += (rr >= m) ? 1 : 0; srcn = rr*KR + KP; }
      float e = ssrc[srcn] + sd;
      e = (e > 0.f) ? e : NEG_SLOPE*e;
      ev[k] = e; mx = fmaxf(mx, e);
    }
    float den = 0.f;
    #pragma unroll
    for (int k = 0; k < 23; ++k) { float ex = __expf(ev[k]-mx); ev[k] = ex; den += ex; }
    float inv = 1.f/den;
    #pragma unroll
    for (int k = 0; k < 23; ++k) alpha[m][k] = ev[k]*inv;
  }
  __syncthreads();
  // aggregate in r-space
  {
    int m = tid >> 5, jq = (tid & 31)*4;
    float4 acc = make_float4(0.f,0.f,0.f,0.f);
    #pragma unroll
    for (int k = 0; k < 23; ++k) {
      int srcn;
      if (k < KP) srcn = m*KR + k;
      else { int rr = k - KP; rr += (rr >= m) ? 1 : 0; srcn = rr*KR + KP; }
      float al = alpha[m][k];
      float4 hv = *(const float4*)&rl[srcn*132 + jq];
      acc.x = fmaf(al, hv.x, acc.x); acc.y = fmaf(al, hv.y, acc.y);
      acc.z = fmaf(al, hv.z, acc.z); acc.w = fmaf(al, hv.w, acc.w);
    }
    *(float4*)&aggR[m][jq] = acc;
  }
  __syncthreads();
  // build V^T: v16[k][row] = (row<8 ? r_root[row][k] : aggR[row-8][k])
  for (int idx = tid; idx < 16*HID; idx += 256) {
    int k = idx & 127, row = idx >> 7;
    float v = (row < 8) ? rl[(row*KR + KP)*132 + k] : aggR[row-8][k];
    v16[k*20 + row] = v;
  }
  __syncthreads();
  // H2 = V(16x128) @ Wg(128x128): thread = (row-half, col j).
  // Wg: one coalesced b32/iter (L2-hot); V^T: all-lane-broadcast float4s.
  {
    int half = tid >> 7, j = tid & 127;
    float acc[8] = {0.f,0.f,0.f,0.f,0.f,0.f,0.f,0.f};
    const float* wgp = Wg + j;
    #pragma unroll 4
    for (int k = 0; k < HID; ++k) {
      float wv = wgp[(size_t)k*HID];
      const float4* vv = (const float4*)&v16[k*20 + half*8];
      float4 va = vv[0], vb = vv[1];
      acc[0] = fmaf(va.x, wv, acc[0]); acc[1] = fmaf(va.y, wv, acc[1]);
      acc[2] = fmaf(va.z, wv, acc[2]); acc[3] = fmaf(va.w, wv, acc[3]);
      acc[4] = fmaf(vb.x, wv, acc[4]); acc[5] = fmaf(vb.y, wv, acc[5]);
      acc[6] = fmaf(vb.z, wv, acc[6]); acc[7] = fmaf(vb.w, wv, acc[7]);
    }
    #pragma unroll
    for (int q = 0; q < 8; ++q) h2[half*8 + q][j] = acc[q];
  }
  __syncthreads();
  // output: leaves elu(H2[m]); roots elu(H2[8+m]); coalesced over j
  {
    int j = tid & 127, half = tid >> 7;
    float* out = rhat + (size_t)bt*NN*HID + j;
    for (int ni = 0; ni < 68; ++ni) {
      int n = half*68 + ni;
      int m = n / KR, kk = n - m*KR;
      float v = (kk < KP) ? h2[m][j] : h2[8+m][j];
      v = (v > 0.f) ? v : (__expf(v) - 1.f);
      out[(size_t)n*HID] = v;
    }
  }
}

// ---------------------------------------------------------------------------
extern "C" void kernel_launch(void* const* d_in, const int* in_sizes, int n_in,
                              void* d_out, int out_size, void* d_ws, size_t ws_size,
                              hipStream_t stream) {
  (void)in_sizes; (void)n_in; (void)out_size; (void)ws_size;
  const float* feat  = (const float*)d_in[0];
  const float* W1    = (const float*)d_in[1];
  const float* b1    = (const float*)d_in[2];
  const float* W2    = (const float*)d_in[3];
  const float* b2    = (const float*)d_in[4];
  const float* W_ih  = (const float*)d_in[5];
  const float* W_hh  = (const float*)d_in[6];
  const float* b_ih  = (const float*)d_in[7];
  const float* b_hh  = (const float*)d_in[8];
  const float* Wg    = (const float*)d_in[9];
  const float* a_src = (const float*)d_in[10];
  const float* a_dst = (const float*)d_in[11];

  float* x    = (float*)d_ws;                       // (T, B*N, EMB) fp32 = 35.7 MB
  float* r    = (float*)d_out;                      // (B, T, N, HID)
  float* rhat = r + (size_t)BB*TB*NN*HID;           // (B, T, N, HID)

  k1_mlp<<<BB*TB, 256, 0, stream>>>(feat, W1, b1, W2, b2, x);
  k2_lstm<<<68, 512, 0, stream>>>(x, W_ih, W_hh, b_ih, b_hh, r);
  k3_gat<<<BB*TB, 256, 0, stream>>>(r, Wg, a_src, a_dst, rhat);
}

// Round 5
// 607.686 us; speedup vs baseline: 1.2196x; 1.1138x over previous
//
#include <hip/hip_runtime.h>

#define TB 128      // T
#define BB 8        // B
#define MM 8        // instruments
#define KP 16       // keypoints per instrument
#define KR 17       // K + root
#define NN 136      // M*KR
#define EMB 64
#define HID 128
#define G4 512      // 4*HID
#define BN 1088     // B*N
#define NEG_SLOPE 0.2f

typedef _Float16 h4 __attribute__((ext_vector_type(4)));
typedef _Float16 h8 __attribute__((ext_vector_type(8)));
typedef float    f4v __attribute__((ext_vector_type(4)));

__device__ __forceinline__ float sigf(float x) { return 1.0f/(1.0f + __expf(-x)); }
__device__ __forceinline__ float tanhf_fast(float x) {
  x = fminf(fmaxf(x, -15.0f), 15.0f);
  float e = __expf(2.0f*x);
  return (e - 1.0f)/(e + 1.0f);
}
// barrier that drains only LDS (lgkm), NOT global stores (vmcnt) — all
// cross-wave data in k2 flows through LDS; global r-stores are fire-and-forget.
__device__ __forceinline__ void bar_lds() {
  asm volatile("s_waitcnt lgkmcnt(0)\n\ts_barrier" ::: "memory");
}

// ---------------------------------------------------------------------------
// K1: root synthesis + 2-layer MLP -> x[t][b*NN+n][e]  (one block per (b,t))
// ---------------------------------------------------------------------------
__global__ __launch_bounds__(256) void k1_mlp(
    const float* __restrict__ feat, const float* __restrict__ W1,
    const float* __restrict__ b1, const float* __restrict__ W2,
    const float* __restrict__ b2, float* __restrict__ x)
{
  __shared__ float fl[MM*KP*3];
  __shared__ float fR[NN][3];
  __shared__ float hidl[NN][EMB];
  const int bt = blockIdx.x;
  const int b = bt >> 7;          // bt / T  (T == 128)
  const int t = bt & 127;
  const int tid = threadIdx.x;

  const float* fp = feat + (size_t)bt * (MM*KP*3);
  for (int i = tid; i < MM*KP*3; i += 256) fl[i] = fp[i];
  __syncthreads();

  if (tid < NN) {
    int n = tid, m = n / KR, kk = n - m*KR;
    if (kk < KP) {
      fR[n][0] = fl[(m*KP+kk)*3+0];
      fR[n][1] = fl[(m*KP+kk)*3+1];
      fR[n][2] = fl[(m*KP+kk)*3+2];
    } else {
      float sx = 0.f, sy = 0.f, sw = 0.f;
      for (int k = 0; k < KP; ++k) {
        float vz = fl[(m*KP+k)*3+2];
        float w = (vz > 0.5f) ? 1.0f : 0.0f;
        sx += fl[(m*KP+k)*3+0]*w;
        sy += fl[(m*KP+k)*3+1]*w;
        sw += w;
      }
      float dn = fmaxf(sw, 1.0f);
      fR[n][0] = sx/dn; fR[n][1] = sy/dn; fR[n][2] = (sw > 0.f) ? 1.f : 0.f;
    }
  }
  __syncthreads();

  const int p = tid & 31, e0 = p*2, nb = tid >> 5;   // 8 row-groups of 17
  float w10a = W1[e0],   w11a = W1[EMB+e0],   w12a = W1[2*EMB+e0],   b1a = b1[e0];
  float w10b = W1[e0+1], w11b = W1[EMB+e0+1], w12b = W1[2*EMB+e0+1], b1b = b1[e0+1];
  for (int ni = 0; ni < 17; ++ni) {
    int n = nb*17 + ni;
    float xx = fR[n][0], yy = fR[n][1], zz = fR[n][2];
    float va = fmaf(xx,w10a, fmaf(yy,w11a, fmaf(zz,w12a, b1a)));
    float vb = fmaf(xx,w10b, fmaf(yy,w11b, fmaf(zz,w12b, b1b)));
    *(float2*)&hidl[n][e0] = make_float2(fmaxf(va,0.f), fmaxf(vb,0.f));
  }
  float2 w2c[EMB];
  #pragma unroll
  for (int j = 0; j < EMB; ++j) w2c[j] = *(const float2*)&W2[(size_t)j*EMB + e0];
  float b2a = b2[e0], b2b = b2[e0+1];
  __syncthreads();

  float* xo = x + ((size_t)t*BN + (size_t)b*NN)*EMB + e0;
  for (int ni = 0; ni < 17; ++ni) {
    int n = nb*17 + ni;
    float aa = b2a, ab = b2b;
    const float4* h4p = (const float4*)hidl[n];
    #pragma unroll
    for (int j4 = 0; j4 < 16; ++j4) {
      float4 hv = h4p[j4];
      aa = fmaf(hv.x, w2c[4*j4+0].x, aa); ab = fmaf(hv.x, w2c[4*j4+0].y, ab);
      aa = fmaf(hv.y, w2c[4*j4+1].x, aa); ab = fmaf(hv.y, w2c[4*j4+1].y, ab);
      aa = fmaf(hv.z, w2c[4*j4+2].x, aa); ab = fmaf(hv.z, w2c[4*j4+2].y, ab);
      aa = fmaf(hv.w, w2c[4*j4+3].x, aa); ab = fmaf(hv.w, w2c[4*j4+3].y, ab);
    }
    *(float2*)&xo[(size_t)n*EMB] = make_float2(aa, ab);
  }
}

// ---------------------------------------------------------------------------
// K2: LSTM on the MATRIX pipe, full-rate shape. 68 blocks x 512 threads
// (8 waves), 16 seqs/blk. z = W_f16 @ (v_hi + v_lo), fp32 MFMA accum.
// ROUND-5 CHANGE: v_mfma_f32_16x16x32_f16 (K=32) instead of the legacy
// 16x16x16 (which measured ~16 cyc/inst = quarter-rate on gfx950; MfmaUtil
// 41%/active-CU for only 192 MFMA/SIMD/step). Halves instruction count AND
// uses the 1955 TF shape.
//   frag maps (16x16x32, m92/m97-verified contiguous-8 layout):
//     A: lane l -> row=l&15, k = 32*kt + 8*(l>>4) + e   (e=0..7)
//     B: lane l -> col=l&15, k = 32*kt + 8*(l>>4) + e
//     C: lane l, reg q -> row=4*(l>>4)+q, col=l&15      (same as K=16 shape)
// B-frags: Bh8/Bl8[kt][lane] 16B entries; read = 1 contiguous ds_read_b128.
// Producer (w,l) [seq=l&15, j0=16w+4(l>>4)] writes its 4 f16 into entry
// l2 = (l&15) + 16*(2*(w&1)+((l>>4)>>1)), half (l>>4)&1
//   [identity: 8*(2(w&1)+(lg>>1)) + 4*(lg&1) = 16(w&1)+4lg = j0 - 32*(w>>1)].
// zlds/gates/z-read indices/bias/r-store: UNCHANGED from round 4 (C layout
// identical; G = 8g + w algebra re-verified).
// ---------------------------------------------------------------------------
__global__ __launch_bounds__(512, 2) void k2_lstm(
    const float* __restrict__ x, const float* __restrict__ W_ih,
    const float* __restrict__ W_hh, const float* __restrict__ b_ih,
    const float* __restrict__ b_hh, float* __restrict__ r)
{
  __shared__ h8  Bh8[6*64];         // v_hi frags [kt][lane]   6 KB
  __shared__ h8  Bl8[6*64];         // v_lo frags [kt][lane]   6 KB
  __shared__ f4v zlds[32*64];       // z [G][lane] (4 rows/lane) 32 KB
  const int tid = threadIdx.x;
  const int w   = tid >> 6;         // wave 0..7
  const int l   = tid & 63;
  const int lr  = l & 15;           // frag row/col  (also: my seq)
  const int lg  = l >> 4;           // k-subgroup    (also: my j-quad)
  const int s0  = blockIdx.x * 16;

  // ---- A-frags: W as f16, rows 64w..64w+63, K=192 in 6 ktiles of 32 ----
  h8 A[4][6];
  #pragma unroll
  for (int m = 0; m < 4; ++m) {
    int row = 64*w + 16*m + lr;
    const float* wih = W_ih + (size_t)row*64;
    const float* whh = W_hh + (size_t)row*128;
    #pragma unroll
    for (int kt = 0; kt < 6; ++kt) {
      int k = kt*32 + lg*8;
      float4 wv0 = (k < 64) ? *(const float4*)(wih + k)
                            : *(const float4*)(whh + (k - 64));
      float4 wv1 = (k+4 < 64) ? *(const float4*)(wih + k + 4)
                              : *(const float4*)(whh + (k + 4 - 64));
      A[m][kt] = h8{(_Float16)wv0.x,(_Float16)wv0.y,(_Float16)wv0.z,(_Float16)wv0.w,
                    (_Float16)wv1.x,(_Float16)wv1.y,(_Float16)wv1.z,(_Float16)wv1.w};
    }
  }
  #pragma unroll
  for (int m = 0; m < 4; ++m)
    #pragma unroll
    for (int kt = 0; kt < 6; ++kt)
      asm volatile("" : "+v"(A[m][kt]));

  // per-wave bias in C layout (pre-added via C-init each step)
  f4v biasC[4];
  #pragma unroll
  for (int m = 0; m < 4; ++m)
    #pragma unroll
    for (int q = 0; q < 4; ++q) {
      int row = 64*w + 16*m + lg*4 + q;
      biasC[m][q] = b_ih[row] + b_hh[row];
    }

  // gate-thread coords: seq = lr, hidden j0..j0+3
  const int j0 = 16*w + 4*lg;
  // B-frag destination for this thread's 4 values (h: ktiles 2..5)
  const int l2    = lr + 16*(2*(w&1) + (lg>>1));
  const int halfB = lg & 1;
  const int hIdx  = (2 + (w>>1))*64 + l2;    // h8 index for h-frag
  const int xIdx  = (w>>1)*64 + l2;          // h8 index for x-frag (w<4)

  // r-store base
  const int qq = s0 + lr;
  const int b  = qq / NN, n = qq - b*NN;
  float* rp0 = r + (((size_t)b*TB)*NN + n)*HID + j0;
  const size_t rstep = (size_t)NN*HID;

  // init: zero h-frag ktiles (2..5), stage x(t=0) frags (waves 0..3)
  {
    h4 z0 = h4{(_Float16)0.f,(_Float16)0.f,(_Float16)0.f,(_Float16)0.f};
    ((h4*)Bh8)[256 + tid] = z0;   // h region = h8 idx 128..383 = h4 idx 256..767
    ((h4*)Bl8)[256 + tid] = z0;
    if (w < 4) {
      float4 xv = *(const float4*)(x + ((size_t)(s0 + lr))*EMB + 16*w + 4*lg);
      h4 xh = h4{(_Float16)xv.x,(_Float16)xv.y,(_Float16)xv.z,(_Float16)xv.w};
      h4 xl = h4{(_Float16)(xv.x-(float)xh[0]),(_Float16)(xv.y-(float)xh[1]),
                 (_Float16)(xv.z-(float)xh[2]),(_Float16)(xv.w-(float)xh[3])};
      ((h4*)&Bh8[xIdx])[halfB] = xh;
      ((h4*)&Bl8[xIdx])[halfB] = xl;
    }
  }
  __syncthreads();

  float c0=0.f, c1=0.f, c2=0.f, c3=0.f;

  for (int t = 0; t < TB; ++t) {
    // prefetch x(t+1) FIRST (oldest vmem entry; its wait won't drain r-stores)
    float4 xpre = make_float4(0.f,0.f,0.f,0.f);
    if (w < 4) {
      int tp = (t+1 < TB) ? t+1 : t;
      xpre = *(const float4*)(x + ((size_t)tp*BN + s0 + lr)*EMB + 16*w + 4*lg);
    }

    // ---- phase 1: z = W@v_hi + W@v_lo, bias in C-init ----
    f4v C[4] = {biasC[0], biasC[1], biasC[2], biasC[3]};
    #pragma unroll
    for (int kt = 0; kt < 6; ++kt) {
      h8 bh = Bh8[kt*64 + l];
      h8 bl = Bl8[kt*64 + l];
      #pragma unroll
      for (int m = 0; m < 4; ++m)
        C[m] = __builtin_amdgcn_mfma_f32_16x16x32_f16(A[m][kt], bh, C[m], 0, 0, 0);
      #pragma unroll
      for (int m = 0; m < 4; ++m)
        C[m] = __builtin_amdgcn_mfma_f32_16x16x32_f16(A[m][kt], bl, C[m], 0, 0, 0);
    }
    #pragma unroll
    for (int m = 0; m < 4; ++m) zlds[(4*w + m)*64 + l] = C[m];
    bar_lds();

    // ---- phase 2: gates + h + r-store + B(t+1) frags ----
    f4v zi = zlds[(0*8 + w)*64 + l];
    f4v zf = zlds[(1*8 + w)*64 + l];
    f4v zg = zlds[(2*8 + w)*64 + l];
    f4v zo = zlds[(3*8 + w)*64 + l];
    float h0,h1,h2,h3;
    { float cc = sigf(zf[0])*c0 + sigf(zi[0])*tanhf_fast(zg[0]); h0 = sigf(zo[0])*tanhf_fast(cc); c0 = cc; }
    { float cc = sigf(zf[1])*c1 + sigf(zi[1])*tanhf_fast(zg[1]); h1 = sigf(zo[1])*tanhf_fast(cc); c1 = cc; }
    { float cc = sigf(zf[2])*c2 + sigf(zi[2])*tanhf_fast(zg[2]); h2 = sigf(zo[2])*tanhf_fast(cc); c2 = cc; }
    { float cc = sigf(zf[3])*c3 + sigf(zi[3])*tanhf_fast(zg[3]); h3 = sigf(zo[3])*tanhf_fast(cc); c3 = cc; }
    *(float4*)(rp0 + (size_t)t*rstep) = make_float4(h0,h1,h2,h3);   // fire-and-forget
    h4 hh = h4{(_Float16)h0,(_Float16)h1,(_Float16)h2,(_Float16)h3};
    h4 hl = h4{(_Float16)(h0-(float)hh[0]),(_Float16)(h1-(float)hh[1]),
               (_Float16)(h2-(float)hh[2]),(_Float16)(h3-(float)hh[3])};
    ((h4*)&Bh8[hIdx])[halfB] = hh;
    ((h4*)&Bl8[hIdx])[halfB] = hl;
    if (w < 4) {   // publish prefetched x(t+1) frags
      h4 xh = h4{(_Float16)xpre.x,(_Float16)xpre.y,(_Float16)xpre.z,(_Float16)xpre.w};
      h4 xl = h4{(_Float16)(xpre.x-(float)xh[0]),(_Float16)(xpre.y-(float)xh[1]),
                 (_Float16)(xpre.z-(float)xh[2]),(_Float16)(xpre.w-(float)xh[3])};
      ((h4*)&Bh8[xIdx])[halfB] = xh;
      ((h4*)&Bl8[xIdx])[halfB] = xl;
    }
    bar_lds();
  }
}

// ---------------------------------------------------------------------------
// K3: GAT. s = r@(Wg@a) matvecs; agg in r-space; ONE 16x128x128 GEMM
// H2=[r_roots;aggR]@Wg with coalesced Wg loads and broadcast V^T from LDS.
// ---------------------------------------------------------------------------
__global__ __launch_bounds__(256) void k3_gat(
    const float* __restrict__ r, const float* __restrict__ Wg,
    const float* __restrict__ a_src, const float* __restrict__ a_dst,
    float* __restrict__ rhat)
{
  __shared__ float rl[NN*132];          // r rows padded to 132 floats (71.8 KB)
  __shared__ float waS[HID], waD[HID];
  __shared__ float ssrc[NN], sdst[NN];
  __shared__ float alpha[MM][24];
  __shared__ float aggR[MM][HID];
  __shared__ float v16[HID*20];         // V^T [k][row], row-pad 20 (16B-aligned)
  __shared__ float h2[16][HID];
  const int bt = blockIdx.x;
  const int tid = threadIdx.x;
  const float* rb = r + (size_t)bt*NN*HID;

  // stage r
  {
    const float4* rb4 = (const float4*)rb;
    for (int i = tid; i < NN*32; i += 256) {
      int n = i >> 5, k4 = i & 31;
      *(float4*)&rl[n*132 + k4*4] = rb4[i];
    }
  }
  // wa = Wg @ a  (two 128-dot columns over 256 threads)
  {
    int half = tid >> 7, j = tid & 127;
    const float* av = half ? a_dst : a_src;
    float acc = 0.f;
    for (int k = 0; k < HID; ++k) acc = fmaf(Wg[(size_t)k*HID + j], av[k], acc);
    if (half) waD[j] = acc; else waS[j] = acc;
  }
  __syncthreads();
  // scores
  for (int job = tid; job < 2*NN; job += 256) {
    int n = job >> 1, which = job & 1;
    const float4* rn = (const float4*)&rl[n*132];
    const float4* wa = (const float4*)(which ? waD : waS);
    float acc = 0.f;
    #pragma unroll
    for (int i = 0; i < 32; ++i) {
      float4 a4 = rn[i], b4 = wa[i];
      acc = fmaf(a4.x,b4.x, fmaf(a4.y,b4.y, fmaf(a4.z,b4.z, fmaf(a4.w,b4.w, acc))));
    }
    if (which) sdst[n] = acc; else ssrc[n] = acc;
  }
  __syncthreads();
  // softmax over each root's 23 incoming edges
  if (tid < MM) {
    int m = tid;
    float sd = sdst[m*KR + KP];
    float ev[23]; float mx = -1e30f;
    #pragma unroll
    for (int k = 0; k < 23; ++k) {
      int srcn;
      if (k < KP) srcn = m*KR + k;
      else { int rr = k - KP; rr += (rr >= m) ? 1 : 0; srcn = rr*KR + KP; }
      float e = ssrc[srcn] + sd;
      e = (e > 0.f) ? e : NEG_SLOPE*e;
      ev[k] = e; mx = fmaxf(mx, e);
    }
    float den = 0.f;
    #pragma unroll
    for (int k = 0; k < 23; ++k) { float ex = __expf(ev[k]-mx); ev[k] = ex; den += ex; }
    float inv = 1.f/den;
    #pragma unroll
    for (int k = 0; k < 23; ++k) alpha[m][k] = ev[k]*inv;
  }
  __syncthreads();
  // aggregate in r-space
  {
    int m = tid >> 5, jq = (tid & 31)*4;
    float4 acc = make_float4(0.f,0.f,0.f,0.f);
    #pragma unroll
    for (int k = 0; k < 23; ++k) {
      int srcn;
      if (k < KP) srcn = m*KR + k;
      else { int rr = k - KP; rr += (rr >= m) ? 1 : 0; srcn = rr*KR + KP; }
      float al = alpha[m][k];
      float4 hv = *(const float4*)&rl[srcn*132 + jq];
      acc.x = fmaf(al, hv.x, acc.x); acc.y = fmaf(al, hv.y, acc.y);
      acc.z = fmaf(al, hv.z, acc.z); acc.w = fmaf(al, hv.w, acc.w);
    }
    *(float4*)&aggR[m][jq] = acc;
  }
  __syncthreads();
  // build V^T: v16[k][row] = (row<8 ? r_root[row][k] : aggR[row-8][k])
  for (int idx = tid; idx < 16*HID; idx += 256) {
    int k = idx & 127, row = idx >> 7;
    float v = (row < 8) ? rl[(row*KR + KP)*132 + k] : aggR[row-8][k];
    v16[k*20 + row] = v;
  }
  __syncthreads();
  // H2 = V(16x128) @ Wg(128x128): thread = (row-half, col j).
  // Wg: one coalesced b32/iter (L2-hot); V^T: all-lane-broadcast float4s.
  {
    int half = tid >> 7, j = tid & 127;
    float acc[8] = {0.f,0.f,0.f,0.f,0.f,0.f,0.f,0.f};
    const float* wgp = Wg + j;
    #pragma unroll 4
    for (int k = 0; k < HID; ++k) {
      float wv = wgp[(size_t)k*HID];
      const float4* vv = (const float4*)&v16[k*20 + half*8];
      float4 va = vv[0], vb = vv[1];
      acc[0] = fmaf(va.x, wv, acc[0]); acc[1] = fmaf(va.y, wv, acc[1]);
      acc[2] = fmaf(va.z, wv, acc[2]); acc[3] = fmaf(va.w, wv, acc[3]);
      acc[4] = fmaf(vb.x, wv, acc[4]); acc[5] = fmaf(vb.y, wv, acc[5]);
      acc[6] = fmaf(vb.z, wv, acc[6]); acc[7] = fmaf(vb.w, wv, acc[7]);
    }
    #pragma unroll
    for (int q = 0; q < 8; ++q) h2[half*8 + q][j] = acc[q];
  }
  __syncthreads();
  // output: leaves elu(H2[m]); roots elu(H2[8+m]); coalesced over j
  {
    int j = tid & 127, half = tid >> 7;
    float* out = rhat + (size_t)bt*NN*HID + j;
    for (int ni = 0; ni < 68; ++ni) {
      int n = half*68 + ni;
      int m = n / KR, kk = n - m*KR;
      float v = (kk < KP) ? h2[m][j] : h2[8+m][j];
      v = (v > 0.f) ? v : (__expf(v) - 1.f);
      out[(size_t)n*HID] = v;
    }
  }
}

// ---------------------------------------------------------------------------
extern "C" void kernel_launch(void* const* d_in, const int* in_sizes, int n_in,
                              void* d_out, int out_size, void* d_ws, size_t ws_size,
                              hipStream_t stream) {
  (void)in_sizes; (void)n_in; (void)out_size; (void)ws_size;
  const float* feat  = (const float*)d_in[0];
  const float* W1    = (const float*)d_in[1];
  const float* b1    = (const float*)d_in[2];
  const float* W2    = (const float*)d_in[3];
  const float* b2    = (const float*)d_in[4];
  const float* W_ih  = (const float*)d_in[5];
  const float* W_hh  = (const float*)d_in[6];
  const float* b_ih  = (const float*)d_in[7];
  const float* b_hh  = (const float*)d_in[8];
  const float* Wg    = (const float*)d_in[9];
  const float* a_src = (const float*)d_in[10];
  const float* a_dst = (const float*)d_in[11];

  float* x    = (float*)d_ws;                       // (T, B*N, EMB) fp32 = 35.7 MB
  float* r    = (float*)d_out;                      // (B, T, N, HID)
  float* rhat = r + (size_t)BB*TB*NN*HID;           // (B, T, N, HID)

  k1_mlp<<<BB*TB, 256, 0, stream>>>(feat, W1, b1, W2, b2, x);
  k2_lstm<<<68, 512, 0, stream>>>(x, W_ih, W_hh, b_ih, b_hh, r);
  k3_gat<<<BB*TB, 256, 0, stream>>>(r, Wg, a_src, a_dst, rhat);
}

// Round 6
// 555.673 us; speedup vs baseline: 1.3338x; 1.0936x over previous
//
#include <hip/hip_runtime.h>

#define TB 128      // T
#define BB 8        // B
#define MM 8        // instruments
#define KP 16       // keypoints per instrument
#define KR 17       // K + root
#define NN 136      // M*KR
#define EMB 64
#define HID 128
#define G4 512      // 4*HID
#define BN 1088     // B*N
#define NEG_SLOPE 0.2f

typedef _Float16 h4 __attribute__((ext_vector_type(4)));
typedef _Float16 h8 __attribute__((ext_vector_type(8)));
typedef float    f4v __attribute__((ext_vector_type(4)));

__device__ __forceinline__ float sigf(float x) { return 1.0f/(1.0f + __expf(-x)); }
__device__ __forceinline__ float tanhf_fast(float x) {
  x = fminf(fmaxf(x, -15.0f), 15.0f);
  float e = __expf(2.0f*x);
  return (e - 1.0f)/(e + 1.0f);
}
// barrier that drains only LDS (lgkm), NOT global stores (vmcnt) — all
// cross-wave data in k2 flows through LDS; global r-stores are fire-and-forget.
__device__ __forceinline__ void bar_lds() {
  asm volatile("s_waitcnt lgkmcnt(0)\n\ts_barrier" ::: "memory");
}

// ---------------------------------------------------------------------------
// K1: root synthesis + 2-layer MLP -> x[t][b*NN+n][e]  (one block per (b,t))
// ---------------------------------------------------------------------------
__global__ __launch_bounds__(256) void k1_mlp(
    const float* __restrict__ feat, const float* __restrict__ W1,
    const float* __restrict__ b1, const float* __restrict__ W2,
    const float* __restrict__ b2, float* __restrict__ x)
{
  __shared__ float fl[MM*KP*3];
  __shared__ float fR[NN][3];
  __shared__ float hidl[NN][EMB];
  const int bt = blockIdx.x;
  const int b = bt >> 7;          // bt / T  (T == 128)
  const int t = bt & 127;
  const int tid = threadIdx.x;

  const float* fp = feat + (size_t)bt * (MM*KP*3);
  for (int i = tid; i < MM*KP*3; i += 256) fl[i] = fp[i];
  __syncthreads();

  if (tid < NN) {
    int n = tid, m = n / KR, kk = n - m*KR;
    if (kk < KP) {
      fR[n][0] = fl[(m*KP+kk)*3+0];
      fR[n][1] = fl[(m*KP+kk)*3+1];
      fR[n][2] = fl[(m*KP+kk)*3+2];
    } else {
      float sx = 0.f, sy = 0.f, sw = 0.f;
      for (int k = 0; k < KP; ++k) {
        float vz = fl[(m*KP+k)*3+2];
        float w = (vz > 0.5f) ? 1.0f : 0.0f;
        sx += fl[(m*KP+k)*3+0]*w;
        sy += fl[(m*KP+k)*3+1]*w;
        sw += w;
      }
      float dn = fmaxf(sw, 1.0f);
      fR[n][0] = sx/dn; fR[n][1] = sy/dn; fR[n][2] = (sw > 0.f) ? 1.f : 0.f;
    }
  }
  __syncthreads();

  const int p = tid & 31, e0 = p*2, nb = tid >> 5;   // 8 row-groups of 17
  float w10a = W1[e0],   w11a = W1[EMB+e0],   w12a = W1[2*EMB+e0],   b1a = b1[e0];
  float w10b = W1[e0+1], w11b = W1[EMB+e0+1], w12b = W1[2*EMB+e0+1], b1b = b1[e0+1];
  for (int ni = 0; ni < 17; ++ni) {
    int n = nb*17 + ni;
    float xx = fR[n][0], yy = fR[n][1], zz = fR[n][2];
    float va = fmaf(xx,w10a, fmaf(yy,w11a, fmaf(zz,w12a, b1a)));
    float vb = fmaf(xx,w10b, fmaf(yy,w11b, fmaf(zz,w12b, b1b)));
    *(float2*)&hidl[n][e0] = make_float2(fmaxf(va,0.f), fmaxf(vb,0.f));
  }
  float2 w2c[EMB];
  #pragma unroll
  for (int j = 0; j < EMB; ++j) w2c[j] = *(const float2*)&W2[(size_t)j*EMB + e0];
  float b2a = b2[e0], b2b = b2[e0+1];
  __syncthreads();

  float* xo = x + ((size_t)t*BN + (size_t)b*NN)*EMB + e0;
  for (int ni = 0; ni < 17; ++ni) {
    int n = nb*17 + ni;
    float aa = b2a, ab = b2b;
    const float4* h4p = (const float4*)hidl[n];
    #pragma unroll
    for (int j4 = 0; j4 < 16; ++j4) {
      float4 hv = h4p[j4];
      aa = fmaf(hv.x, w2c[4*j4+0].x, aa); ab = fmaf(hv.x, w2c[4*j4+0].y, ab);
      aa = fmaf(hv.y, w2c[4*j4+1].x, aa); ab = fmaf(hv.y, w2c[4*j4+1].y, ab);
      aa = fmaf(hv.z, w2c[4*j4+2].x, aa); ab = fmaf(hv.z, w2c[4*j4+2].y, ab);
      aa = fmaf(hv.w, w2c[4*j4+3].x, aa); ab = fmaf(hv.w, w2c[4*j4+3].y, ab);
    }
    *(float2*)&xo[(size_t)n*EMB] = make_float2(aa, ab);
  }
}

// ---------------------------------------------------------------------------
// K2: LSTM, MFMA, register-resident gates. 68 blocks x 512 threads (8 waves),
// 16 seqs/blk. z = W_f16 @ (v_hi + v_lo), fp32 MFMA accum, 16x16x32 shape.
// ROUND-6 RESTRUCTURE (was: zlds round-trip + 2 barriers/step):
//  * Wave w owns A-rows {128g + 16w + [0,16) : g=0..3} — one M-tile PER GATE.
//    By the C layout (row=4*(l>>4)+q, col=l&15), thread (w,l) ends phase 1
//    holding i,f,g,o for j = 16w+4*(l>>4)+q, seq = l&15 in C[0..3][q] regs.
//    zlds (32 KB + write + read + barrier) is DELETED.
//  * B-frag buffers ping-pong by step parity: step t reads buf[t&1], writes
//    buf[1-(t&1)] -> ONE bar_lds per step (lgkmcnt(0) before s_barrier makes
//    this race-free: all reads of a buffer complete before the barrier that
//    precedes any writes to it).
//  * x-part off the critical path: C_pre(t+1) = bias + W_x@x(t+1) (2 ktiles,
//    16 MFMAs) computed AFTER the gates from frags staged one step earlier;
//    the critical phase is only the 4 h-ktiles (32 MFMAs).
// Producer-side frag formulas (hEnt/xEnt/l2/halfB) are UNCHANGED from the
// round-4/5 verified layout:
//   B: lane l -> col=l&15, k = 32*kt + 8*(l>>4) + e  (e=0..7)
//   writer (w,l) [seq=l&15, j0=16w+4*(l>>4)]: l2=(l&15)+16*(2*(w&1)+((l>>4)>>1)),
//   half=(l>>4)&1, h at entry (2+(w>>1))*64+l2, x at (w>>1)*64+l2.
// ---------------------------------------------------------------------------
__global__ __launch_bounds__(512, 2) void k2_lstm(
    const float* __restrict__ x, const float* __restrict__ W_ih,
    const float* __restrict__ W_hh, const float* __restrict__ b_ih,
    const float* __restrict__ b_hh, float* __restrict__ r)
{
  __shared__ h8  Bh8[2][6*64];      // [parity][kt][lane] v_hi frags  12 KB
  __shared__ h8  Bl8[2][6*64];      // [parity][kt][lane] v_lo frags  12 KB
  const int tid = threadIdx.x;
  const int w   = tid >> 6;         // wave 0..7
  const int l   = tid & 63;
  const int lr  = l & 15;           // frag col  (= my seq)
  const int lg  = l >> 4;           // k-subgroup (= my j-quad)
  const int s0  = blockIdx.x * 16;

  // ---- A-frags: W as f16, rows 128g+16w+lr, K=192 in 6 ktiles of 32 ----
  h8 A[4][6];
  #pragma unroll
  for (int g = 0; g < 4; ++g) {
    int row = 128*g + 16*w + lr;
    const float* wih = W_ih + (size_t)row*64;
    const float* whh = W_hh + (size_t)row*128;
    #pragma unroll
    for (int kt = 0; kt < 6; ++kt) {
      int k = kt*32 + lg*8;
      float4 wv0 = (k < 64) ? *(const float4*)(wih + k)
                            : *(const float4*)(whh + (k - 64));
      float4 wv1 = (k+4 < 64) ? *(const float4*)(wih + k + 4)
                              : *(const float4*)(whh + (k + 4 - 64));
      A[g][kt] = h8{(_Float16)wv0.x,(_Float16)wv0.y,(_Float16)wv0.z,(_Float16)wv0.w,
                    (_Float16)wv1.x,(_Float16)wv1.y,(_Float16)wv1.z,(_Float16)wv1.w};
    }
  }
  #pragma unroll
  for (int g = 0; g < 4; ++g)
    #pragma unroll
    for (int kt = 0; kt < 6; ++kt)
      asm volatile("" : "+v"(A[g][kt]));

  // bias in C layout: biasC[g][q] = b[128g + 16w + 4lg + q]
  f4v biasC[4];
  #pragma unroll
  for (int g = 0; g < 4; ++g)
    #pragma unroll
    for (int q = 0; q < 4; ++q) {
      int row = 128*g + 16*w + 4*lg + q;
      biasC[g][q] = b_ih[row] + b_hh[row];
    }

  // producer-side frag coordinates (verified layout, unchanged)
  const int j0    = 16*w + 4*lg;
  const int l2    = lr + 16*(2*(w&1) + (lg>>1));
  const int halfB = lg & 1;
  const int hEnt  = (2 + (w>>1))*64 + l2;    // h-frag entry (ktiles 2..5)
  const int xEnt  = (w>>1)*64 + l2;          // x-frag entry (ktiles 0..1, w<4)

  // r-store base
  const int qq = s0 + lr;
  const int b  = qq / NN, n = qq - b*NN;
  float* rp0 = r + (((size_t)b*TB)*NN + n)*HID + j0;
  const size_t rstep = (size_t)NN*HID;

  // ---- init: zero h-region of buf0; stage x(0) into buf0 x-region ----
  {
    h4 z0 = h4{(_Float16)0.f,(_Float16)0.f,(_Float16)0.f,(_Float16)0.f};
    ((h4*)&Bh8[0][0])[256 + tid] = z0;   // h-region = h8 128..383 = h4 256..767
    ((h4*)&Bl8[0][0])[256 + tid] = z0;
    if (w < 4) {
      float4 xv = *(const float4*)(x + ((size_t)(s0 + lr))*EMB + 16*w + 4*lg);
      h4 xh = h4{(_Float16)xv.x,(_Float16)xv.y,(_Float16)xv.z,(_Float16)xv.w};
      h4 xl = h4{(_Float16)(xv.x-(float)xh[0]),(_Float16)(xv.y-(float)xh[1]),
                 (_Float16)(xv.z-(float)xh[2]),(_Float16)(xv.w-(float)xh[3])};
      ((h4*)&Bh8[0][xEnt])[halfB] = xh;
      ((h4*)&Bl8[0][xEnt])[halfB] = xl;
    }
  }
  __syncthreads();

  // C_pre(0) = bias + W_x @ x(0)  (from buf0 x-region)
  f4v Cp[4] = {biasC[0], biasC[1], biasC[2], biasC[3]};
  #pragma unroll
  for (int kt = 0; kt < 2; ++kt) {
    h8 bh = Bh8[0][kt*64 + l];
    h8 bl = Bl8[0][kt*64 + l];
    #pragma unroll
    for (int g = 0; g < 4; ++g)
      Cp[g] = __builtin_amdgcn_mfma_f32_16x16x32_f16(A[g][kt], bh, Cp[g], 0, 0, 0);
    #pragma unroll
    for (int g = 0; g < 4; ++g)
      Cp[g] = __builtin_amdgcn_mfma_f32_16x16x32_f16(A[g][kt], bl, Cp[g], 0, 0, 0);
  }
  __syncthreads();                 // all waves done reading x(0) frags
  if (w < 4) {                     // overwrite buf0 x-region with x(1)
    float4 xv = *(const float4*)(x + ((size_t)BN + s0 + lr)*EMB + 16*w + 4*lg);
    h4 xh = h4{(_Float16)xv.x,(_Float16)xv.y,(_Float16)xv.z,(_Float16)xv.w};
    h4 xl = h4{(_Float16)(xv.x-(float)xh[0]),(_Float16)(xv.y-(float)xh[1]),
               (_Float16)(xv.z-(float)xh[2]),(_Float16)(xv.w-(float)xh[3])};
    ((h4*)&Bh8[0][xEnt])[halfB] = xh;
    ((h4*)&Bl8[0][xEnt])[halfB] = xl;
  }
  __syncthreads();

  float c0=0.f, c1=0.f, c2=0.f, c3=0.f;

  for (int t = 0; t < TB; ++t) {
    const int p = t & 1;
    // prefetch x(t+2) FIRST (oldest vmem entry; its wait won't drain r-stores)
    float4 xpre = make_float4(0.f,0.f,0.f,0.f);
    if (w < 4) {
      int tp = (t+2 < TB) ? t+2 : TB-1;
      xpre = *(const float4*)(x + ((size_t)tp*BN + s0 + lr)*EMB + 16*w + 4*lg);
    }

    // ---- critical: z(t) = C_pre(t) + W_h @ h(t-1)  (4 h-ktiles) ----
    f4v C[4] = {Cp[0], Cp[1], Cp[2], Cp[3]};
    #pragma unroll
    for (int kt = 2; kt < 6; ++kt) {
      h8 bh = Bh8[p][kt*64 + l];
      h8 bl = Bl8[p][kt*64 + l];
      #pragma unroll
      for (int g = 0; g < 4; ++g)
        C[g] = __builtin_amdgcn_mfma_f32_16x16x32_f16(A[g][kt], bh, C[g], 0, 0, 0);
      #pragma unroll
      for (int g = 0; g < 4; ++g)
        C[g] = __builtin_amdgcn_mfma_f32_16x16x32_f16(A[g][kt], bl, C[g], 0, 0, 0);
    }

    // issue x(t+1) frag reads early — latency hides under the gate VALU
    h8 xbh0 = Bh8[p][0*64 + l], xbl0 = Bl8[p][0*64 + l];
    h8 xbh1 = Bh8[p][1*64 + l], xbl1 = Bl8[p][1*64 + l];

    // ---- gates directly from C registers (no LDS round-trip) ----
    f4v zi = C[0], zf = C[1], zg = C[2], zo = C[3];
    float h0,h1,h2,h3;
    { float cc = sigf(zf[0])*c0 + sigf(zi[0])*tanhf_fast(zg[0]); h0 = sigf(zo[0])*tanhf_fast(cc); c0 = cc; }
    { float cc = sigf(zf[1])*c1 + sigf(zi[1])*tanhf_fast(zg[1]); h1 = sigf(zo[1])*tanhf_fast(cc); c1 = cc; }
    { float cc = sigf(zf[2])*c2 + sigf(zi[2])*tanhf_fast(zg[2]); h2 = sigf(zo[2])*tanhf_fast(cc); c2 = cc; }
    { float cc = sigf(zf[3])*c3 + sigf(zi[3])*tanhf_fast(zg[3]); h3 = sigf(zo[3])*tanhf_fast(cc); c3 = cc; }
    *(float4*)(rp0 + (size_t)t*rstep) = make_float4(h0,h1,h2,h3);   // fire-and-forget
    h4 hh = h4{(_Float16)h0,(_Float16)h1,(_Float16)h2,(_Float16)h3};
    h4 hl = h4{(_Float16)(h0-(float)hh[0]),(_Float16)(h1-(float)hh[1]),
               (_Float16)(h2-(float)hh[2]),(_Float16)(h3-(float)hh[3])};
    ((h4*)&Bh8[1-p][hEnt])[halfB] = hh;
    ((h4*)&Bl8[1-p][hEnt])[halfB] = hl;

    // ---- off-path: C_pre(t+1) = bias + W_x @ x(t+1) ----
    Cp[0] = biasC[0]; Cp[1] = biasC[1]; Cp[2] = biasC[2]; Cp[3] = biasC[3];
    #pragma unroll
    for (int g = 0; g < 4; ++g)
      Cp[g] = __builtin_amdgcn_mfma_f32_16x16x32_f16(A[g][0], xbh0, Cp[g], 0, 0, 0);
    #pragma unroll
    for (int g = 0; g < 4; ++g)
      Cp[g] = __builtin_amdgcn_mfma_f32_16x16x32_f16(A[g][0], xbl0, Cp[g], 0, 0, 0);
    #pragma unroll
    for (int g = 0; g < 4; ++g)
      Cp[g] = __builtin_amdgcn_mfma_f32_16x16x32_f16(A[g][1], xbh1, Cp[g], 0, 0, 0);
    #pragma unroll
    for (int g = 0; g < 4; ++g)
      Cp[g] = __builtin_amdgcn_mfma_f32_16x16x32_f16(A[g][1], xbl1, Cp[g], 0, 0, 0);

    // publish prefetched x(t+2) frags into the write buffer
    if (w < 4) {
      h4 xh = h4{(_Float16)xpre.x,(_Float16)xpre.y,(_Float16)xpre.z,(_Float16)xpre.w};
      h4 xl = h4{(_Float16)(xpre.x-(float)xh[0]),(_Float16)(xpre.y-(float)xh[1]),
                 (_Float16)(xpre.z-(float)xh[2]),(_Float16)(xpre.w-(float)xh[3])};
      ((h4*)&Bh8[1-p][xEnt])[halfB] = xh;
      ((h4*)&Bl8[1-p][xEnt])[halfB] = xl;
    }
    bar_lds();    // the ONLY barrier per step
  }
}

// ---------------------------------------------------------------------------
// K3: GAT. s = r@(Wg@a) matvecs; agg in r-space; ONE 16x128x128 GEMM
// H2=[r_roots;aggR]@Wg with coalesced Wg loads and broadcast V^T from LDS.
// ---------------------------------------------------------------------------
__global__ __launch_bounds__(256) void k3_gat(
    const float* __restrict__ r, const float* __restrict__ Wg,
    const float* __restrict__ a_src, const float* __restrict__ a_dst,
    float* __restrict__ rhat)
{
  __shared__ float rl[NN*132];          // r rows padded to 132 floats (71.8 KB)
  __shared__ float waS[HID], waD[HID];
  __shared__ float ssrc[NN], sdst[NN];
  __shared__ float alpha[MM][24];
  __shared__ float aggR[MM][HID];
  __shared__ float v16[HID*20];         // V^T [k][row], row-pad 20 (16B-aligned)
  __shared__ float h2[16][HID];
  const int bt = blockIdx.x;
  const int tid = threadIdx.x;
  const float* rb = r + (size_t)bt*NN*HID;

  // stage r
  {
    const float4* rb4 = (const float4*)rb;
    for (int i = tid; i < NN*32; i += 256) {
      int n = i >> 5, k4 = i & 31;
      *(float4*)&rl[n*132 + k4*4] = rb4[i];
    }
  }
  // wa = Wg @ a  (two 128-dot columns over 256 threads)
  {
    int half = tid >> 7, j = tid & 127;
    const float* av = half ? a_dst : a_src;
    float acc = 0.f;
    for (int k = 0; k < HID; ++k) acc = fmaf(Wg[(size_t)k*HID + j], av[k], acc);
    if (half) waD[j] = acc; else waS[j] = acc;
  }
  __syncthreads();
  // scores
  for (int job = tid; job < 2*NN; job += 256) {
    int n = job >> 1, which = job & 1;
    const float4* rn = (const float4*)&rl[n*132];
    const float4* wa = (const float4*)(which ? waD : waS);
    float acc = 0.f;
    #pragma unroll
    for (int i = 0; i < 32; ++i) {
      float4 a4 = rn[i], b4 = wa[i];
      acc = fmaf(a4.x,b4.x, fmaf(a4.y,b4.y, fmaf(a4.z,b4.z, fmaf(a4.w,b4.w, acc))));
    }
    if (which) sdst[n] = acc; else ssrc[n] = acc;
  }
  __syncthreads();
  // softmax over each root's 23 incoming edges
  if (tid < MM) {
    int m = tid;
    float sd = sdst[m*KR + KP];
    float ev[23]; float mx = -1e30f;
    #pragma unroll
    for (int k = 0; k < 23; ++k) {
      int srcn;
      if (k < KP) srcn = m*KR + k;
      else { int rr = k - KP; rr += (rr >= m) ? 1 : 0; srcn = rr*KR + KP; }
      float e = ssrc[srcn] + sd;
      e = (e > 0.f) ? e : NEG_SLOPE*e;
      ev[k] = e; mx = fmaxf(mx, e);
    }
    float den = 0.f;
    #pragma unroll
    for (int k = 0; k < 23; ++k) { float ex = __expf(ev[k]-mx); ev[k] = ex; den += ex; }
    float inv = 1.f/den;
    #pragma unroll
    for (int k = 0; k < 23; ++k) alpha[m][k] = ev[k]*inv;
  }
  __syncthreads();
  // aggregate in r-space
  {
    int m = tid >> 5, jq = (tid & 31)*4;
    float4 acc = make_float4(0.f,0.f,0.f,0.f);
    #pragma unroll
    for (int k = 0; k < 23; ++k) {
      int srcn;
      if (k < KP) srcn = m*KR + k;
      else { int rr = k - KP; rr += (rr >= m) ? 1 : 0; srcn = rr*KR + KP; }
      float al = alpha[m][k];
      float4 hv = *(const float4*)&rl[srcn*132 + jq];
      acc.x = fmaf(al, hv.x, acc.x); acc.y = fmaf(al, hv.y, acc.y);
      acc.z = fmaf(al, hv.z, acc.z); acc.w = fmaf(al, hv.w, acc.w);
    }
    *(float4*)&aggR[m][jq] = acc;
  }
  __syncthreads();
  // build V^T: v16[k][row] = (row<8 ? r_root[row][k] : aggR[row-8][k])
  for (int idx = tid; idx < 16*HID; idx += 256) {
    int k = idx & 127, row = idx >> 7;
    float v = (row < 8) ? rl[(row*KR + KP)*132 + k] : aggR[row-8][k];
    v16[k*20 + row] = v;
  }
  __syncthreads();
  // H2 = V(16x128) @ Wg(128x128): thread = (row-half, col j).
  // Wg: one coalesced b32/iter (L2-hot); V^T: all-lane-broadcast float4s.
  {
    int half = tid >> 7, j = tid & 127;
    float acc[8] = {0.f,0.f,0.f,0.f,0.f,0.f,0.f,0.f};
    const float* wgp = Wg + j;
    #pragma unroll 4
    for (int k = 0; k < HID; ++k) {
      float wv = wgp[(size_t)k*HID];
      const float4* vv = (const float4*)&v16[k*20 + half*8];
      float4 va = vv[0], vb = vv[1];
      acc[0] = fmaf(va.x, wv, acc[0]); acc[1] = fmaf(va.y, wv, acc[1]);
      acc[2] = fmaf(va.z, wv, acc[2]); acc[3] = fmaf(va.w, wv, acc[3]);
      acc[4] = fmaf(vb.x, wv, acc[4]); acc[5] = fmaf(vb.y, wv, acc[5]);
      acc[6] = fmaf(vb.z, wv, acc[6]); acc[7] = fmaf(vb.w, wv, acc[7]);
    }
    #pragma unroll
    for (int q = 0; q < 8; ++q) h2[half*8 + q][j] = acc[q];
  }
  __syncthreads();
  // output: leaves elu(H2[m]); roots elu(H2[8+m]); coalesced over j
  {
    int j = tid & 127, half = tid >> 7;
    float* out = rhat + (size_t)bt*NN*HID + j;
    for (int ni = 0; ni < 68; ++ni) {
      int n = half*68 + ni;
      int m = n / KR, kk = n - m*KR;
      float v = (kk < KP) ? h2[m][j] : h2[8+m][j];
      v = (v > 0.f) ? v : (__expf(v) - 1.f);
      out[(size_t)n*HID] = v;
    }
  }
}

// ---------------------------------------------------------------------------
extern "C" void kernel_launch(void* const* d_in, const int* in_sizes, int n_in,
                              void* d_out, int out_size, void* d_ws, size_t ws_size,
                              hipStream_t stream) {
  (void)in_sizes; (void)n_in; (void)out_size; (void)ws_size;
  const float* feat  = (const float*)d_in[0];
  const float* W1    = (const float*)d_in[1];
  const float* b1    = (const float*)d_in[2];
  const float* W2    = (const float*)d_in[3];
  const float* b2    = (const float*)d_in[4];
  const float* W_ih  = (const float*)d_in[5];
  const float* W_hh  = (const float*)d_in[6];
  const float* b_ih  = (const float*)d_in[7];
  const float* b_hh  = (const float*)d_in[8];
  const float* Wg    = (const float*)d_in[9];
  const float* a_src = (const float*)d_in[10];
  const float* a_dst = (const float*)d_in[11];

  float* x    = (float*)d_ws;                       // (T, B*N, EMB) fp32 = 35.7 MB
  float* r    = (float*)d_out;                      // (B, T, N, HID)
  float* rhat = r + (size_t)BB*TB*NN*HID;           // (B, T, N, HID)

  k1_mlp<<<BB*TB, 256, 0, stream>>>(feat, W1, b1, W2, b2, x);
  k2_lstm<<<68, 512, 0, stream>>>(x, W_ih, W_hh, b_ih, b_hh, r);
  k3_gat<<<BB*TB, 256, 0, stream>>>(r, Wg, a_src, a_dst, rhat);
}

// Round 8
// 538.898 us; speedup vs baseline: 1.3753x; 1.0311x over previous
//
#include <hip/hip_runtime.h>

#define TB 128      // T
#define BB 8        // B
#define MM 8        // instruments
#define KP 16       // keypoints per instrument
#define KR 17       // K + root
#define NN 136      // M*KR
#define EMB 64
#define HID 128
#define G4 512      // 4*HID
#define BN 1088     // B*N
#define NEG_SLOPE 0.2f

typedef _Float16 h4 __attribute__((ext_vector_type(4)));
typedef _Float16 h8 __attribute__((ext_vector_type(8)));
typedef float    f4v __attribute__((ext_vector_type(4)));

__device__ __forceinline__ float sigf(float x) { return 1.0f/(1.0f + __expf(-x)); }
__device__ __forceinline__ float tanhf_fast(float x) {
  x = fminf(fmaxf(x, -15.0f), 15.0f);
  float e = __expf(2.0f*x);
  return (e - 1.0f)/(e + 1.0f);
}
// barrier that drains only LDS (lgkm), NOT global stores (vmcnt) — all
// cross-wave data in k2 flows through LDS; global r-stores are fire-and-forget.
__device__ __forceinline__ void bar_lds() {
  asm volatile("s_waitcnt lgkmcnt(0)\n\ts_barrier" ::: "memory");
}

// ---------------------------------------------------------------------------
// K1: root synthesis + 2-layer MLP -> x[t][b*NN+n][e]  (one block per (b,t))
// ---------------------------------------------------------------------------
__global__ __launch_bounds__(256) void k1_mlp(
    const float* __restrict__ feat, const float* __restrict__ W1,
    const float* __restrict__ b1, const float* __restrict__ W2,
    const float* __restrict__ b2, float* __restrict__ x)
{
  __shared__ float fl[MM*KP*3];
  __shared__ float fR[NN][3];
  __shared__ float hidl[NN][EMB];
  const int bt = blockIdx.x;
  const int b = bt >> 7;          // bt / T  (T == 128)
  const int t = bt & 127;
  const int tid = threadIdx.x;

  const float* fp = feat + (size_t)bt * (MM*KP*3);
  for (int i = tid; i < MM*KP*3; i += 256) fl[i] = fp[i];
  __syncthreads();

  if (tid < NN) {
    int n = tid, m = n / KR, kk = n - m*KR;
    if (kk < KP) {
      fR[n][0] = fl[(m*KP+kk)*3+0];
      fR[n][1] = fl[(m*KP+kk)*3+1];
      fR[n][2] = fl[(m*KP+kk)*3+2];
    } else {
      float sx = 0.f, sy = 0.f, sw = 0.f;
      for (int k = 0; k < KP; ++k) {
        float vz = fl[(m*KP+k)*3+2];
        float w = (vz > 0.5f) ? 1.0f : 0.0f;
        sx += fl[(m*KP+k)*3+0]*w;
        sy += fl[(m*KP+k)*3+1]*w;
        sw += w;
      }
      float dn = fmaxf(sw, 1.0f);
      fR[n][0] = sx/dn; fR[n][1] = sy/dn; fR[n][2] = (sw > 0.f) ? 1.f : 0.f;
    }
  }
  __syncthreads();

  const int p = tid & 31, e0 = p*2, nb = tid >> 5;   // 8 row-groups of 17
  float w10a = W1[e0],   w11a = W1[EMB+e0],   w12a = W1[2*EMB+e0],   b1a = b1[e0];
  float w10b = W1[e0+1], w11b = W1[EMB+e0+1], w12b = W1[2*EMB+e0+1], b1b = b1[e0+1];
  for (int ni = 0; ni < 17; ++ni) {
    int n = nb*17 + ni;
    float xx = fR[n][0], yy = fR[n][1], zz = fR[n][2];
    float va = fmaf(xx,w10a, fmaf(yy,w11a, fmaf(zz,w12a, b1a)));
    float vb = fmaf(xx,w10b, fmaf(yy,w11b, fmaf(zz,w12b, b1b)));
    *(float2*)&hidl[n][e0] = make_float2(fmaxf(va,0.f), fmaxf(vb,0.f));
  }
  float2 w2c[EMB];
  #pragma unroll
  for (int j = 0; j < EMB; ++j) w2c[j] = *(const float2*)&W2[(size_t)j*EMB + e0];
  float b2a = b2[e0], b2b = b2[e0+1];
  __syncthreads();

  float* xo = x + ((size_t)t*BN + (size_t)b*NN)*EMB + e0;
  for (int ni = 0; ni < 17; ++ni) {
    int n = nb*17 + ni;
    float aa = b2a, ab = b2b;
    const float4* h4p = (const float4*)hidl[n];
    #pragma unroll
    for (int j4 = 0; j4 < 16; ++j4) {
      float4 hv = h4p[j4];
      aa = fmaf(hv.x, w2c[4*j4+0].x, aa); ab = fmaf(hv.x, w2c[4*j4+0].y, ab);
      aa = fmaf(hv.y, w2c[4*j4+1].x, aa); ab = fmaf(hv.y, w2c[4*j4+1].y, ab);
      aa = fmaf(hv.z, w2c[4*j4+2].x, aa); ab = fmaf(hv.z, w2c[4*j4+2].y, ab);
      aa = fmaf(hv.w, w2c[4*j4+3].x, aa); ab = fmaf(hv.w, w2c[4*j4+3].y, ab);
    }
    *(float2*)&xo[(size_t)n*EMB] = make_float2(aa, ab);
  }
}

// ---------------------------------------------------------------------------
// K2: LSTM, MFMA, register-resident gates. 68 blocks x 512 threads (8 waves),
// 16 seqs/blk. UNCHANGED from round 6 (clean A/B vs the k3 change).
// ---------------------------------------------------------------------------
__global__ __launch_bounds__(512, 2) void k2_lstm(
    const float* __restrict__ x, const float* __restrict__ W_ih,
    const float* __restrict__ W_hh, const float* __restrict__ b_ih,
    const float* __restrict__ b_hh, float* __restrict__ r)
{
  __shared__ h8  Bh8[2][6*64];      // [parity][kt][lane] v_hi frags  12 KB
  __shared__ h8  Bl8[2][6*64];      // [parity][kt][lane] v_lo frags  12 KB
  const int tid = threadIdx.x;
  const int w   = tid >> 6;         // wave 0..7
  const int l   = tid & 63;
  const int lr  = l & 15;           // frag col  (= my seq)
  const int lg  = l >> 4;           // k-subgroup (= my j-quad)
  const int s0  = blockIdx.x * 16;

  // ---- A-frags: W as f16, rows 128g+16w+lr, K=192 in 6 ktiles of 32 ----
  h8 A[4][6];
  #pragma unroll
  for (int g = 0; g < 4; ++g) {
    int row = 128*g + 16*w + lr;
    const float* wih = W_ih + (size_t)row*64;
    const float* whh = W_hh + (size_t)row*128;
    #pragma unroll
    for (int kt = 0; kt < 6; ++kt) {
      int k = kt*32 + lg*8;
      float4 wv0 = (k < 64) ? *(const float4*)(wih + k)
                            : *(const float4*)(whh + (k - 64));
      float4 wv1 = (k+4 < 64) ? *(const float4*)(wih + k + 4)
                              : *(const float4*)(whh + (k + 4 - 64));
      A[g][kt] = h8{(_Float16)wv0.x,(_Float16)wv0.y,(_Float16)wv0.z,(_Float16)wv0.w,
                    (_Float16)wv1.x,(_Float16)wv1.y,(_Float16)wv1.z,(_Float16)wv1.w};
    }
  }
  #pragma unroll
  for (int g = 0; g < 4; ++g)
    #pragma unroll
    for (int kt = 0; kt < 6; ++kt)
      asm volatile("" : "+v"(A[g][kt]));

  // bias in C layout: biasC[g][q] = b[128g + 16w + 4lg + q]
  f4v biasC[4];
  #pragma unroll
  for (int g = 0; g < 4; ++g)
    #pragma unroll
    for (int q = 0; q < 4; ++q) {
      int row = 128*g + 16*w + 4*lg + q;
      biasC[g][q] = b_ih[row] + b_hh[row];
    }

  // producer-side frag coordinates (verified layout, unchanged)
  const int j0    = 16*w + 4*lg;
  const int l2    = lr + 16*(2*(w&1) + (lg>>1));
  const int halfB = lg & 1;
  const int hEnt  = (2 + (w>>1))*64 + l2;    // h-frag entry (ktiles 2..5)
  const int xEnt  = (w>>1)*64 + l2;          // x-frag entry (ktiles 0..1, w<4)

  // r-store base
  const int qq = s0 + lr;
  const int b  = qq / NN, n = qq - b*NN;
  float* rp0 = r + (((size_t)b*TB)*NN + n)*HID + j0;
  const size_t rstep = (size_t)NN*HID;

  // ---- init: zero h-region of buf0; stage x(0) into buf0 x-region ----
  {
    h4 z0 = h4{(_Float16)0.f,(_Float16)0.f,(_Float16)0.f,(_Float16)0.f};
    ((h4*)&Bh8[0][0])[256 + tid] = z0;   // h-region = h8 128..383 = h4 256..767
    ((h4*)&Bl8[0][0])[256 + tid] = z0;
    if (w < 4) {
      float4 xv = *(const float4*)(x + ((size_t)(s0 + lr))*EMB + 16*w + 4*lg);
      h4 xh = h4{(_Float16)xv.x,(_Float16)xv.y,(_Float16)xv.z,(_Float16)xv.w};
      h4 xl = h4{(_Float16)(xv.x-(float)xh[0]),(_Float16)(xv.y-(float)xh[1]),
                 (_Float16)(xv.z-(float)xh[2]),(_Float16)(xv.w-(float)xh[3])};
      ((h4*)&Bh8[0][xEnt])[halfB] = xh;
      ((h4*)&Bl8[0][xEnt])[halfB] = xl;
    }
  }
  __syncthreads();

  // C_pre(0) = bias + W_x @ x(0)  (from buf0 x-region)
  f4v Cp[4] = {biasC[0], biasC[1], biasC[2], biasC[3]};
  #pragma unroll
  for (int kt = 0; kt < 2; ++kt) {
    h8 bh = Bh8[0][kt*64 + l];
    h8 bl = Bl8[0][kt*64 + l];
    #pragma unroll
    for (int g = 0; g < 4; ++g)
      Cp[g] = __builtin_amdgcn_mfma_f32_16x16x32_f16(A[g][kt], bh, Cp[g], 0, 0, 0);
    #pragma unroll
    for (int g = 0; g < 4; ++g)
      Cp[g] = __builtin_amdgcn_mfma_f32_16x16x32_f16(A[g][kt], bl, Cp[g], 0, 0, 0);
  }
  __syncthreads();                 // all waves done reading x(0) frags
  if (w < 4) {                     // overwrite buf0 x-region with x(1)
    float4 xv = *(const float4*)(x + ((size_t)BN + s0 + lr)*EMB + 16*w + 4*lg);
    h4 xh = h4{(_Float16)xv.x,(_Float16)xv.y,(_Float16)xv.z,(_Float16)xv.w};
    h4 xl = h4{(_Float16)(xv.x-(float)xh[0]),(_Float16)(xv.y-(float)xh[1]),
               (_Float16)(xv.z-(float)xh[2]),(_Float16)(xv.w-(float)xh[3])};
    ((h4*)&Bh8[0][xEnt])[halfB] = xh;
    ((h4*)&Bl8[0][xEnt])[halfB] = xl;
  }
  __syncthreads();

  float c0=0.f, c1=0.f, c2=0.f, c3=0.f;

  for (int t = 0; t < TB; ++t) {
    const int p = t & 1;
    // prefetch x(t+2) FIRST (oldest vmem entry; its wait won't drain r-stores)
    float4 xpre = make_float4(0.f,0.f,0.f,0.f);
    if (w < 4) {
      int tp = (t+2 < TB) ? t+2 : TB-1;
      xpre = *(const float4*)(x + ((size_t)tp*BN + s0 + lr)*EMB + 16*w + 4*lg);
    }

    // ---- critical: z(t) = C_pre(t) + W_h @ h(t-1)  (4 h-ktiles) ----
    f4v C[4] = {Cp[0], Cp[1], Cp[2], Cp[3]};
    #pragma unroll
    for (int kt = 2; kt < 6; ++kt) {
      h8 bh = Bh8[p][kt*64 + l];
      h8 bl = Bl8[p][kt*64 + l];
      #pragma unroll
      for (int g = 0; g < 4; ++g)
        C[g] = __builtin_amdgcn_mfma_f32_16x16x32_f16(A[g][kt], bh, C[g], 0, 0, 0);
      #pragma unroll
      for (int g = 0; g < 4; ++g)
        C[g] = __builtin_amdgcn_mfma_f32_16x16x32_f16(A[g][kt], bl, C[g], 0, 0, 0);
    }

    // issue x(t+1) frag reads early — latency hides under the gate VALU
    h8 xbh0 = Bh8[p][0*64 + l], xbl0 = Bl8[p][0*64 + l];
    h8 xbh1 = Bh8[p][1*64 + l], xbl1 = Bl8[p][1*64 + l];

    // ---- gates directly from C registers (no LDS round-trip) ----
    f4v zi = C[0], zf = C[1], zg = C[2], zo = C[3];
    float h0,h1,h2,h3;
    { float cc = sigf(zf[0])*c0 + sigf(zi[0])*tanhf_fast(zg[0]); h0 = sigf(zo[0])*tanhf_fast(cc); c0 = cc; }
    { float cc = sigf(zf[1])*c1 + sigf(zi[1])*tanhf_fast(zg[1]); h1 = sigf(zo[1])*tanhf_fast(cc); c1 = cc; }
    { float cc = sigf(zf[2])*c2 + sigf(zi[2])*tanhf_fast(zg[2]); h2 = sigf(zo[2])*tanhf_fast(cc); c2 = cc; }
    { float cc = sigf(zf[3])*c3 + sigf(zi[3])*tanhf_fast(zg[3]); h3 = sigf(zo[3])*tanhf_fast(cc); c3 = cc; }
    *(float4*)(rp0 + (size_t)t*rstep) = make_float4(h0,h1,h2,h3);   // fire-and-forget
    h4 hh = h4{(_Float16)h0,(_Float16)h1,(_Float16)h2,(_Float16)h3};
    h4 hl = h4{(_Float16)(h0-(float)hh[0]),(_Float16)(h1-(float)hh[1]),
               (_Float16)(h2-(float)hh[2]),(_Float16)(h3-(float)hh[3])};
    ((h4*)&Bh8[1-p][hEnt])[halfB] = hh;
    ((h4*)&Bl8[1-p][hEnt])[halfB] = hl;

    // ---- off-path: C_pre(t+1) = bias + W_x @ x(t+1) ----
    Cp[0] = biasC[0]; Cp[1] = biasC[1]; Cp[2] = biasC[2]; Cp[3] = biasC[3];
    #pragma unroll
    for (int g = 0; g < 4; ++g)
      Cp[g] = __builtin_amdgcn_mfma_f32_16x16x32_f16(A[g][0], xbh0, Cp[g], 0, 0, 0);
    #pragma unroll
    for (int g = 0; g < 4; ++g)
      Cp[g] = __builtin_amdgcn_mfma_f32_16x16x32_f16(A[g][0], xbl0, Cp[g], 0, 0, 0);
    #pragma unroll
    for (int g = 0; g < 4; ++g)
      Cp[g] = __builtin_amdgcn_mfma_f32_16x16x32_f16(A[g][1], xbh1, Cp[g], 0, 0, 0);
    #pragma unroll
    for (int g = 0; g < 4; ++g)
      Cp[g] = __builtin_amdgcn_mfma_f32_16x16x32_f16(A[g][1], xbl1, Cp[g], 0, 0, 0);

    // publish prefetched x(t+2) frags into the write buffer
    if (w < 4) {
      h4 xh = h4{(_Float16)xpre.x,(_Float16)xpre.y,(_Float16)xpre.z,(_Float16)xpre.w};
      h4 xl = h4{(_Float16)(xpre.x-(float)xh[0]),(_Float16)(xpre.y-(float)xh[1]),
                 (_Float16)(xpre.z-(float)xh[2]),(_Float16)(xpre.w-(float)xh[3])};
      ((h4*)&Bh8[1-p][xEnt])[halfB] = xh;
      ((h4*)&Bl8[1-p][xEnt])[halfB] = xl;
    }
    bar_lds();    // the ONLY barrier per step
  }
}

// ---------------------------------------------------------------------------
// K3: GAT. ROUND-8 (= round-7 resubmit after infra flake): 512 threads
// (was 256). Same ~95 KB LDS keeps 1 block/CU, but waves/SIMD go 1 -> 2 and
// every serial phase's per-thread work halves:
//   agg: 64 threads/m, float2; H2: 4 row-quarters x acc[4]; output: 4 x 34 rows.
// Algorithm and LDS layout unchanged.
// ---------------------------------------------------------------------------
__global__ __launch_bounds__(512) void k3_gat(
    const float* __restrict__ r, const float* __restrict__ Wg,
    const float* __restrict__ a_src, const float* __restrict__ a_dst,
    float* __restrict__ rhat)
{
  __shared__ float rl[NN*132];          // r rows padded to 132 floats (71.8 KB)
  __shared__ float waS[HID], waD[HID];
  __shared__ float ssrc[NN], sdst[NN];
  __shared__ float alpha[MM][24];
  __shared__ float aggR[MM][HID];
  __shared__ float v16[HID*20];         // V^T [k][row], row-pad 20 (16B-aligned)
  __shared__ float h2[16][HID];
  const int bt = blockIdx.x;
  const int tid = threadIdx.x;
  const float* rb = r + (size_t)bt*NN*HID;

  // stage r (512-wide strided)
  {
    const float4* rb4 = (const float4*)rb;
    for (int i = tid; i < NN*32; i += 512) {
      int n = i >> 5, k4 = i & 31;
      *(float4*)&rl[n*132 + k4*4] = rb4[i];
    }
  }
  // wa = Wg @ a  (two 128-dot columns; threads 256..511 idle here — cost tiny)
  if (tid < 256) {
    int half = tid >> 7, j = tid & 127;
    const float* av = half ? a_dst : a_src;
    float acc = 0.f;
    for (int k = 0; k < HID; ++k) acc = fmaf(Wg[(size_t)k*HID + j], av[k], acc);
    if (half) waD[j] = acc; else waS[j] = acc;
  }
  __syncthreads();
  // scores: 272 jobs over 512 threads (single pass)
  for (int job = tid; job < 2*NN; job += 512) {
    int n = job >> 1, which = job & 1;
    const float4* rn = (const float4*)&rl[n*132];
    const float4* wa = (const float4*)(which ? waD : waS);
    float acc = 0.f;
    #pragma unroll
    for (int i = 0; i < 32; ++i) {
      float4 a4 = rn[i], b4 = wa[i];
      acc = fmaf(a4.x,b4.x, fmaf(a4.y,b4.y, fmaf(a4.z,b4.z, fmaf(a4.w,b4.w, acc))));
    }
    if (which) sdst[n] = acc; else ssrc[n] = acc;
  }
  __syncthreads();
  // softmax over each root's 23 incoming edges
  if (tid < MM) {
    int m = tid;
    float sd = sdst[m*KR + KP];
    float ev[23]; float mx = -1e30f;
    #pragma unroll
    for (int k = 0; k < 23; ++k) {
      int srcn;
      if (k < KP) srcn = m*KR + k;
      else { int rr = k - KP; rr += (rr >= m) ? 1 : 0; srcn = rr*KR + KP; }
      float e = ssrc[srcn] + sd;
      e = (e > 0.f) ? e : NEG_SLOPE*e;
      ev[k] = e; mx = fmaxf(mx, e);
    }
    float den = 0.f;
    #pragma unroll
    for (int k = 0; k < 23; ++k) { float ex = __expf(ev[k]-mx); ev[k] = ex; den += ex; }
    float inv = 1.f/den;
    #pragma unroll
    for (int k = 0; k < 23; ++k) alpha[m][k] = ev[k]*inv;
  }
  __syncthreads();
  // aggregate in r-space: 64 threads per m, float2 per thread
  {
    int m = tid >> 6, jq = (tid & 63)*2;
    float2 acc = make_float2(0.f,0.f);
    #pragma unroll
    for (int k = 0; k < 23; ++k) {
      int srcn;
      if (k < KP) srcn = m*KR + k;
      else { int rr = k - KP; rr += (rr >= m) ? 1 : 0; srcn = rr*KR + KP; }
      float al = alpha[m][k];
      float2 hv = *(const float2*)&rl[srcn*132 + jq];
      acc.x = fmaf(al, hv.x, acc.x); acc.y = fmaf(al, hv.y, acc.y);
    }
    *(float2*)&aggR[m][jq] = acc;
  }
  __syncthreads();
  // build V^T: v16[k][row] = (row<8 ? r_root[row][k] : aggR[row-8][k])
  for (int idx = tid; idx < 16*HID; idx += 512) {
    int k = idx & 127, row = idx >> 7;
    float v = (row < 8) ? rl[(row*KR + KP)*132 + k] : aggR[row-8][k];
    v16[k*20 + row] = v;
  }
  __syncthreads();
  // H2 = V(16x128) @ Wg(128x128): thread = (row-quarter qr, col j), acc[4].
  // Wg: one coalesced b32/iter (L1/L2-hot); V^T: broadcast float4 (16B-aligned:
  // byte off = 80k + 16qr).
  {
    int qr = tid >> 7, j = tid & 127;
    float acc[4] = {0.f,0.f,0.f,0.f};
    const float* wgp = Wg + j;
    #pragma unroll 4
    for (int k = 0; k < HID; ++k) {
      float wv = wgp[(size_t)k*HID];
      float4 va = *(const float4*)&v16[k*20 + qr*4];
      acc[0] = fmaf(va.x, wv, acc[0]); acc[1] = fmaf(va.y, wv, acc[1]);
      acc[2] = fmaf(va.z, wv, acc[2]); acc[3] = fmaf(va.w, wv, acc[3]);
    }
    #pragma unroll
    for (int q = 0; q < 4; ++q) h2[qr*4 + q][j] = acc[q];
  }
  __syncthreads();
  // output: leaves elu(H2[m]); roots elu(H2[8+m]); 4 quarters x 34 rows
  {
    int j = tid & 127, qr = tid >> 7;
    float* out = rhat + (size_t)bt*NN*HID + j;
    for (int ni = 0; ni < 34; ++ni) {
      int n = qr*34 + ni;
      int m = n / KR, kk = n - m*KR;
      float v = (kk < KP) ? h2[m][j] : h2[8+m][j];
      v = (v > 0.f) ? v : (__expf(v) - 1.f);
      out[(size_t)n*HID] = v;
    }
  }
}

// ---------------------------------------------------------------------------
extern "C" void kernel_launch(void* const* d_in, const int* in_sizes, int n_in,
                              void* d_out, int out_size, void* d_ws, size_t ws_size,
                              hipStream_t stream) {
  (void)in_sizes; (void)n_in; (void)out_size; (void)ws_size;
  const float* feat  = (const float*)d_in[0];
  const float* W1    = (const float*)d_in[1];
  const float* b1    = (const float*)d_in[2];
  const float* W2    = (const float*)d_in[3];
  const float* b2    = (const float*)d_in[4];
  const float* W_ih  = (const float*)d_in[5];
  const float* W_hh  = (const float*)d_in[6];
  const float* b_ih  = (const float*)d_in[7];
  const float* b_hh  = (const float*)d_in[8];
  const float* Wg    = (const float*)d_in[9];
  const float* a_src = (const float*)d_in[10];
  const float* a_dst = (const float*)d_in[11];

  float* x    = (float*)d_ws;                       // (T, B*N, EMB) fp32 = 35.7 MB
  float* r    = (float*)d_out;                      // (B, T, N, HID)
  float* rhat = r + (size_t)BB*TB*NN*HID;           // (B, T, N, HID)

  k1_mlp<<<BB*TB, 256, 0, stream>>>(feat, W1, b1, W2, b2, x);
  k2_lstm<<<68, 512, 0, stream>>>(x, W_ih, W_hh, b_ih, b_hh, r);
  k3_gat<<<BB*TB, 512, 0, stream>>>(r, Wg, a_src, a_dst, rhat);
}

// Round 9
// 498.781 us; speedup vs baseline: 1.4859x; 1.0804x over previous
//
#include <hip/hip_runtime.h>

#define TB 128      // T
#define BB 8        // B
#define MM 8        // instruments
#define KP 16       // keypoints per instrument
#define KR 17       // K + root
#define NN 136      // M*KR
#define EMB 64
#define HID 128
#define G4 512      // 4*HID
#define BN 1088     // B*N
#define NEG_SLOPE 0.2f

typedef _Float16 h4 __attribute__((ext_vector_type(4)));
typedef _Float16 h8 __attribute__((ext_vector_type(8)));
typedef float    f4v __attribute__((ext_vector_type(4)));

__device__ __forceinline__ float sigf(float x) { return 1.0f/(1.0f + __expf(-x)); }
__device__ __forceinline__ float tanhf_fast(float x) {
  x = fminf(fmaxf(x, -15.0f), 15.0f);
  float e = __expf(2.0f*x);
  return (e - 1.0f)/(e + 1.0f);
}
// barrier that drains only LDS (lgkm), NOT global stores (vmcnt) — all
// cross-wave data in k2 flows through LDS; global r-stores are fire-and-forget.
__device__ __forceinline__ void bar_lds() {
  asm volatile("s_waitcnt lgkmcnt(0)\n\ts_barrier" ::: "memory");
}

// split a fp32 octet into hi/lo f16 fragments (exact to ~2^-22 combined)
__device__ __forceinline__ void cvt_hilo(const float4 a0, const float4 a1,
                                         h8& hi, h8& lo) {
  hi = h8{(_Float16)a0.x,(_Float16)a0.y,(_Float16)a0.z,(_Float16)a0.w,
          (_Float16)a1.x,(_Float16)a1.y,(_Float16)a1.z,(_Float16)a1.w};
  lo = h8{(_Float16)(a0.x-(float)hi[0]),(_Float16)(a0.y-(float)hi[1]),
          (_Float16)(a0.z-(float)hi[2]),(_Float16)(a0.w-(float)hi[3]),
          (_Float16)(a1.x-(float)hi[4]),(_Float16)(a1.y-(float)hi[5]),
          (_Float16)(a1.z-(float)hi[6]),(_Float16)(a1.w-(float)hi[7])};
}

// ---------------------------------------------------------------------------
// K1: root synthesis + 2-layer MLP -> x[t][b*NN+n][e]  (one block per (b,t))
// ROUND-9: layer-2 moved to MFMA (16x16x32 f16, SAME frag convention k2 has
// verified for 4 rounds). A = hidl hi/lo, B = W2^T hi/lo, 3-term product
// (AhBh+AhBl+AlBh; AlBl ~2^-22 dropped) -> error ~1e-6: absmax must stay
// 6.1e-5. Replaces the 17-row serial loop (64-deep fp32 dep chain, 128-VGPR
// w2c preload, uniform-b128 hidl broadcasts). W2 transposed once into LDS;
// pad 68 floats/row = 16B-aligned rows + <=2-way bank aliasing (free).
// Wave w owns column-tile nt=w (B-frags converted once); mt = 0..8 (rows
// padded to 144, zeroed tail, stores guarded n<NN).
// ---------------------------------------------------------------------------
__global__ __launch_bounds__(256) void k1_mlp(
    const float* __restrict__ feat, const float* __restrict__ W1,
    const float* __restrict__ b1, const float* __restrict__ W2,
    const float* __restrict__ b2, float* __restrict__ x)
{
  __shared__ float fl[MM*KP*3];
  __shared__ float fR[NN][3];
  __shared__ float hidl[144][68];   // layer-1 out, padded rows/cols (38.3 KB)
  __shared__ float w2t[64][68];     // w2t[e][j] = W2[j][e]        (17.0 KB)
  const int bt = blockIdx.x;
  const int b = bt >> 7;          // bt / T  (T == 128)
  const int t = bt & 127;
  const int tid = threadIdx.x;

  const float* fp = feat + (size_t)bt * (MM*KP*3);
  for (int i = tid; i < MM*KP*3; i += 256) fl[i] = fp[i];
  // transpose W2 into LDS (reads coalesced over e; writes 2-way aliased = free)
  for (int i = tid; i < 64*64; i += 256) {
    int j = i >> 6, e = i & 63;
    w2t[e][j] = W2[(size_t)j*EMB + e];
  }
  // zero the padded tail rows of hidl (rows 136..143)
  for (int i = tid; i < 8*68; i += 256) hidl[136 + i/68][i - (i/68)*68] = 0.f;
  __syncthreads();

  if (tid < NN) {
    int n = tid, m = n / KR, kk = n - m*KR;
    if (kk < KP) {
      fR[n][0] = fl[(m*KP+kk)*3+0];
      fR[n][1] = fl[(m*KP+kk)*3+1];
      fR[n][2] = fl[(m*KP+kk)*3+2];
    } else {
      float sx = 0.f, sy = 0.f, sw = 0.f;
      for (int k = 0; k < KP; ++k) {
        float vz = fl[(m*KP+k)*3+2];
        float w = (vz > 0.5f) ? 1.0f : 0.0f;
        sx += fl[(m*KP+k)*3+0]*w;
        sy += fl[(m*KP+k)*3+1]*w;
        sw += w;
      }
      float dn = fmaxf(sw, 1.0f);
      fR[n][0] = sx/dn; fR[n][1] = sy/dn; fR[n][2] = (sw > 0.f) ? 1.f : 0.f;
    }
  }
  __syncthreads();

  // layer 1 (unchanged math; hidl now stride-68)
  {
    const int p = tid & 31, e0 = p*2, nb = tid >> 5;   // 8 row-groups of 17
    float w10a = W1[e0],   w11a = W1[EMB+e0],   w12a = W1[2*EMB+e0],   b1a = b1[e0];
    float w10b = W1[e0+1], w11b = W1[EMB+e0+1], w12b = W1[2*EMB+e0+1], b1b = b1[e0+1];
    for (int ni = 0; ni < 17; ++ni) {
      int n = nb*17 + ni;
      float xx = fR[n][0], yy = fR[n][1], zz = fR[n][2];
      float va = fmaf(xx,w10a, fmaf(yy,w11a, fmaf(zz,w12a, b1a)));
      float vb = fmaf(xx,w10b, fmaf(yy,w11b, fmaf(zz,w12b, b1b)));
      *(float2*)&hidl[n][e0] = make_float2(fmaxf(va,0.f), fmaxf(vb,0.f));
    }
  }
  __syncthreads();

  // layer 2: x[n][e] = hidl[n][:] @ W2[:, e] + b2[e]  via MFMA
  {
    const int w = tid >> 6, l = tid & 63, lr = l & 15, lg = l >> 4;
    // B-frags for this wave's column tile (cols 16w..16w+15), both ktiles
    h8 Bh[2], Bl[2];
    #pragma unroll
    for (int kt = 0; kt < 2; ++kt) {
      const float* bp = &w2t[16*w + lr][32*kt + 8*lg];
      cvt_hilo(*(const float4*)bp, *(const float4*)(bp+4), Bh[kt], Bl[kt]);
    }
    const float b2v = b2[16*w + lr];
    float* xo = x + ((size_t)t*BN + (size_t)b*NN)*EMB + 16*w + lr;
    #pragma unroll
    for (int mt = 0; mt < 9; ++mt) {
      f4v C = {0.f,0.f,0.f,0.f};
      #pragma unroll
      for (int kt = 0; kt < 2; ++kt) {
        const float* ap = &hidl[16*mt + lr][32*kt + 8*lg];
        h8 Ah, Al; cvt_hilo(*(const float4*)ap, *(const float4*)(ap+4), Ah, Al);
        C = __builtin_amdgcn_mfma_f32_16x16x32_f16(Ah, Bh[kt], C, 0, 0, 0);
        C = __builtin_amdgcn_mfma_f32_16x16x32_f16(Ah, Bl[kt], C, 0, 0, 0);
        C = __builtin_amdgcn_mfma_f32_16x16x32_f16(Al, Bh[kt], C, 0, 0, 0);
      }
      #pragma unroll
      for (int q = 0; q < 4; ++q) {
        int n = 16*mt + 4*lg + q;
        if (n < NN) xo[(size_t)n*EMB] = C[q] + b2v;
      }
    }
  }
}

// ---------------------------------------------------------------------------
// K2: LSTM, MFMA, register-resident gates. 68 blocks x 512 threads (8 waves),
// 16 seqs/blk. UNCHANGED from round 6 (clean A/B vs the k1 change).
// ---------------------------------------------------------------------------
__global__ __launch_bounds__(512, 2) void k2_lstm(
    const float* __restrict__ x, const float* __restrict__ W_ih,
    const float* __restrict__ W_hh, const float* __restrict__ b_ih,
    const float* __restrict__ b_hh, float* __restrict__ r)
{
  __shared__ h8  Bh8[2][6*64];      // [parity][kt][lane] v_hi frags  12 KB
  __shared__ h8  Bl8[2][6*64];      // [parity][kt][lane] v_lo frags  12 KB
  const int tid = threadIdx.x;
  const int w   = tid >> 6;         // wave 0..7
  const int l   = tid & 63;
  const int lr  = l & 15;           // frag col  (= my seq)
  const int lg  = l >> 4;           // k-subgroup (= my j-quad)
  const int s0  = blockIdx.x * 16;

  // ---- A-frags: W as f16, rows 128g+16w+lr, K=192 in 6 ktiles of 32 ----
  h8 A[4][6];
  #pragma unroll
  for (int g = 0; g < 4; ++g) {
    int row = 128*g + 16*w + lr;
    const float* wih = W_ih + (size_t)row*64;
    const float* whh = W_hh + (size_t)row*128;
    #pragma unroll
    for (int kt = 0; kt < 6; ++kt) {
      int k = kt*32 + lg*8;
      float4 wv0 = (k < 64) ? *(const float4*)(wih + k)
                            : *(const float4*)(whh + (k - 64));
      float4 wv1 = (k+4 < 64) ? *(const float4*)(wih + k + 4)
                              : *(const float4*)(whh + (k + 4 - 64));
      A[g][kt] = h8{(_Float16)wv0.x,(_Float16)wv0.y,(_Float16)wv0.z,(_Float16)wv0.w,
                    (_Float16)wv1.x,(_Float16)wv1.y,(_Float16)wv1.z,(_Float16)wv1.w};
    }
  }
  #pragma unroll
  for (int g = 0; g < 4; ++g)
    #pragma unroll
    for (int kt = 0; kt < 6; ++kt)
      asm volatile("" : "+v"(A[g][kt]));

  // bias in C layout: biasC[g][q] = b[128g + 16w + 4lg + q]
  f4v biasC[4];
  #pragma unroll
  for (int g = 0; g < 4; ++g)
    #pragma unroll
    for (int q = 0; q < 4; ++q) {
      int row = 128*g + 16*w + 4*lg + q;
      biasC[g][q] = b_ih[row] + b_hh[row];
    }

  // producer-side frag coordinates (verified layout, unchanged)
  const int j0    = 16*w + 4*lg;
  const int l2    = lr + 16*(2*(w&1) + (lg>>1));
  const int halfB = lg & 1;
  const int hEnt  = (2 + (w>>1))*64 + l2;    // h-frag entry (ktiles 2..5)
  const int xEnt  = (w>>1)*64 + l2;          // x-frag entry (ktiles 0..1, w<4)

  // r-store base
  const int qq = s0 + lr;
  const int b  = qq / NN, n = qq - b*NN;
  float* rp0 = r + (((size_t)b*TB)*NN + n)*HID + j0;
  const size_t rstep = (size_t)NN*HID;

  // ---- init: zero h-region of buf0; stage x(0) into buf0 x-region ----
  {
    h4 z0 = h4{(_Float16)0.f,(_Float16)0.f,(_Float16)0.f,(_Float16)0.f};
    ((h4*)&Bh8[0][0])[256 + tid] = z0;   // h-region = h8 128..383 = h4 256..767
    ((h4*)&Bl8[0][0])[256 + tid] = z0;
    if (w < 4) {
      float4 xv = *(const float4*)(x + ((size_t)(s0 + lr))*EMB + 16*w + 4*lg);
      h4 xh = h4{(_Float16)xv.x,(_Float16)xv.y,(_Float16)xv.z,(_Float16)xv.w};
      h4 xl = h4{(_Float16)(xv.x-(float)xh[0]),(_Float16)(xv.y-(float)xh[1]),
                 (_Float16)(xv.z-(float)xh[2]),(_Float16)(xv.w-(float)xh[3])};
      ((h4*)&Bh8[0][xEnt])[halfB] = xh;
      ((h4*)&Bl8[0][xEnt])[halfB] = xl;
    }
  }
  __syncthreads();

  // C_pre(0) = bias + W_x @ x(0)  (from buf0 x-region)
  f4v Cp[4] = {biasC[0], biasC[1], biasC[2], biasC[3]};
  #pragma unroll
  for (int kt = 0; kt < 2; ++kt) {
    h8 bh = Bh8[0][kt*64 + l];
    h8 bl = Bl8[0][kt*64 + l];
    #pragma unroll
    for (int g = 0; g < 4; ++g)
      Cp[g] = __builtin_amdgcn_mfma_f32_16x16x32_f16(A[g][kt], bh, Cp[g], 0, 0, 0);
    #pragma unroll
    for (int g = 0; g < 4; ++g)
      Cp[g] = __builtin_amdgcn_mfma_f32_16x16x32_f16(A[g][kt], bl, Cp[g], 0, 0, 0);
  }
  __syncthreads();                 // all waves done reading x(0) frags
  if (w < 4) {                     // overwrite buf0 x-region with x(1)
    float4 xv = *(const float4*)(x + ((size_t)BN + s0 + lr)*EMB + 16*w + 4*lg);
    h4 xh = h4{(_Float16)xv.x,(_Float16)xv.y,(_Float16)xv.z,(_Float16)xv.w};
    h4 xl = h4{(_Float16)(xv.x-(float)xh[0]),(_Float16)(xv.y-(float)xh[1]),
               (_Float16)(xv.z-(float)xh[2]),(_Float16)(xv.w-(float)xh[3])};
    ((h4*)&Bh8[0][xEnt])[halfB] = xh;
    ((h4*)&Bl8[0][xEnt])[halfB] = xl;
  }
  __syncthreads();

  float c0=0.f, c1=0.f, c2=0.f, c3=0.f;

  for (int t = 0; t < TB; ++t) {
    const int p = t & 1;
    // prefetch x(t+2) FIRST (oldest vmem entry; its wait won't drain r-stores)
    float4 xpre = make_float4(0.f,0.f,0.f,0.f);
    if (w < 4) {
      int tp = (t+2 < TB) ? t+2 : TB-1;
      xpre = *(const float4*)(x + ((size_t)tp*BN + s0 + lr)*EMB + 16*w + 4*lg);
    }

    // ---- critical: z(t) = C_pre(t) + W_h @ h(t-1)  (4 h-ktiles) ----
    f4v C[4] = {Cp[0], Cp[1], Cp[2], Cp[3]};
    #pragma unroll
    for (int kt = 2; kt < 6; ++kt) {
      h8 bh = Bh8[p][kt*64 + l];
      h8 bl = Bl8[p][kt*64 + l];
      #pragma unroll
      for (int g = 0; g < 4; ++g)
        C[g] = __builtin_amdgcn_mfma_f32_16x16x32_f16(A[g][kt], bh, C[g], 0, 0, 0);
      #pragma unroll
      for (int g = 0; g < 4; ++g)
        C[g] = __builtin_amdgcn_mfma_f32_16x16x32_f16(A[g][kt], bl, C[g], 0, 0, 0);
    }

    // issue x(t+1) frag reads early — latency hides under the gate VALU
    h8 xbh0 = Bh8[p][0*64 + l], xbl0 = Bl8[p][0*64 + l];
    h8 xbh1 = Bh8[p][1*64 + l], xbl1 = Bl8[p][1*64 + l];

    // ---- gates directly from C registers (no LDS round-trip) ----
    f4v zi = C[0], zf = C[1], zg = C[2], zo = C[3];
    float h0,h1,h2,h3;
    { float cc = sigf(zf[0])*c0 + sigf(zi[0])*tanhf_fast(zg[0]); h0 = sigf(zo[0])*tanhf_fast(cc); c0 = cc; }
    { float cc = sigf(zf[1])*c1 + sigf(zi[1])*tanhf_fast(zg[1]); h1 = sigf(zo[1])*tanhf_fast(cc); c1 = cc; }
    { float cc = sigf(zf[2])*c2 + sigf(zi[2])*tanhf_fast(zg[2]); h2 = sigf(zo[2])*tanhf_fast(cc); c2 = cc; }
    { float cc = sigf(zf[3])*c3 + sigf(zi[3])*tanhf_fast(zg[3]); h3 = sigf(zo[3])*tanhf_fast(cc); c3 = cc; }
    *(float4*)(rp0 + (size_t)t*rstep) = make_float4(h0,h1,h2,h3);   // fire-and-forget
    h4 hh = h4{(_Float16)h0,(_Float16)h1,(_Float16)h2,(_Float16)h3};
    h4 hl = h4{(_Float16)(h0-(float)hh[0]),(_Float16)(h1-(float)hh[1]),
               (_Float16)(h2-(float)hh[2]),(_Float16)(h3-(float)hh[3])};
    ((h4*)&Bh8[1-p][hEnt])[halfB] = hh;
    ((h4*)&Bl8[1-p][hEnt])[halfB] = hl;

    // ---- off-path: C_pre(t+1) = bias + W_x @ x(t+1) ----
    Cp[0] = biasC[0]; Cp[1] = biasC[1]; Cp[2] = biasC[2]; Cp[3] = biasC[3];
    #pragma unroll
    for (int g = 0; g < 4; ++g)
      Cp[g] = __builtin_amdgcn_mfma_f32_16x16x32_f16(A[g][0], xbh0, Cp[g], 0, 0, 0);
    #pragma unroll
    for (int g = 0; g < 4; ++g)
      Cp[g] = __builtin_amdgcn_mfma_f32_16x16x32_f16(A[g][0], xbl0, Cp[g], 0, 0, 0);
    #pragma unroll
    for (int g = 0; g < 4; ++g)
      Cp[g] = __builtin_amdgcn_mfma_f32_16x16x32_f16(A[g][1], xbh1, Cp[g], 0, 0, 0);
    #pragma unroll
    for (int g = 0; g < 4; ++g)
      Cp[g] = __builtin_amdgcn_mfma_f32_16x16x32_f16(A[g][1], xbl1, Cp[g], 0, 0, 0);

    // publish prefetched x(t+2) frags into the write buffer
    if (w < 4) {
      h4 xh = h4{(_Float16)xpre.x,(_Float16)xpre.y,(_Float16)xpre.z,(_Float16)xpre.w};
      h4 xl = h4{(_Float16)(xpre.x-(float)xh[0]),(_Float16)(xpre.y-(float)xh[1]),
                 (_Float16)(xpre.z-(float)xh[2]),(_Float16)(xpre.w-(float)xh[3])};
      ((h4*)&Bh8[1-p][xEnt])[halfB] = xh;
      ((h4*)&Bl8[1-p][xEnt])[halfB] = xl;
    }
    bar_lds();    // the ONLY barrier per step
  }
}

// ---------------------------------------------------------------------------
// K3: GAT. UNCHANGED from round 8 (512 threads).
// ---------------------------------------------------------------------------
__global__ __launch_bounds__(512) void k3_gat(
    const float* __restrict__ r, const float* __restrict__ Wg,
    const float* __restrict__ a_src, const float* __restrict__ a_dst,
    float* __restrict__ rhat)
{
  __shared__ float rl[NN*132];          // r rows padded to 132 floats (71.8 KB)
  __shared__ float waS[HID], waD[HID];
  __shared__ float ssrc[NN], sdst[NN];
  __shared__ float alpha[MM][24];
  __shared__ float aggR[MM][HID];
  __shared__ float v16[HID*20];         // V^T [k][row], row-pad 20 (16B-aligned)
  __shared__ float h2[16][HID];
  const int bt = blockIdx.x;
  const int tid = threadIdx.x;
  const float* rb = r + (size_t)bt*NN*HID;

  // stage r (512-wide strided)
  {
    const float4* rb4 = (const float4*)rb;
    for (int i = tid; i < NN*32; i += 512) {
      int n = i >> 5, k4 = i & 31;
      *(float4*)&rl[n*132 + k4*4] = rb4[i];
    }
  }
  // wa = Wg @ a  (two 128-dot columns; threads 256..511 idle here — cost tiny)
  if (tid < 256) {
    int half = tid >> 7, j = tid & 127;
    const float* av = half ? a_dst : a_src;
    float acc = 0.f;
    for (int k = 0; k < HID; ++k) acc = fmaf(Wg[(size_t)k*HID + j], av[k], acc);
    if (half) waD[j] = acc; else waS[j] = acc;
  }
  __syncthreads();
  // scores: 272 jobs over 512 threads (single pass)
  for (int job = tid; job < 2*NN; job += 512) {
    int n = job >> 1, which = job & 1;
    const float4* rn = (const float4*)&rl[n*132];
    const float4* wa = (const float4*)(which ? waD : waS);
    float acc = 0.f;
    #pragma unroll
    for (int i = 0; i < 32; ++i) {
      float4 a4 = rn[i], b4 = wa[i];
      acc = fmaf(a4.x,b4.x, fmaf(a4.y,b4.y, fmaf(a4.z,b4.z, fmaf(a4.w,b4.w, acc))));
    }
    if (which) sdst[n] = acc; else ssrc[n] = acc;
  }
  __syncthreads();
  // softmax over each root's 23 incoming edges
  if (tid < MM) {
    int m = tid;
    float sd = sdst[m*KR + KP];
    float ev[23]; float mx = -1e30f;
    #pragma unroll
    for (int k = 0; k < 23; ++k) {
      int srcn;
      if (k < KP) srcn = m*KR + k;
      else { int rr = k - KP; rr += (rr >= m) ? 1 : 0; srcn = rr*KR + KP; }
      float e = ssrc[srcn] + sd;
      e = (e > 0.f) ? e : NEG_SLOPE*e;
      ev[k] = e; mx = fmaxf(mx, e);
    }
    float den = 0.f;
    #pragma unroll
    for (int k = 0; k < 23; ++k) { float ex = __expf(ev[k]-mx); ev[k] = ex; den += ex; }
    float inv = 1.f/den;
    #pragma unroll
    for (int k = 0; k < 23; ++k) alpha[m][k] = ev[k]*inv;
  }
  __syncthreads();
  // aggregate in r-space: 64 threads per m, float2 per thread
  {
    int m = tid >> 6, jq = (tid & 63)*2;
    float2 acc = make_float2(0.f,0.f);
    #pragma unroll
    for (int k = 0; k < 23; ++k) {
      int srcn;
      if (k < KP) srcn = m*KR + k;
      else { int rr = k - KP; rr += (rr >= m) ? 1 : 0; srcn = rr*KR + KP; }
      float al = alpha[m][k];
      float2 hv = *(const float2*)&rl[srcn*132 + jq];
      acc.x = fmaf(al, hv.x, acc.x); acc.y = fmaf(al, hv.y, acc.y);
    }
    *(float2*)&aggR[m][jq] = acc;
  }
  __syncthreads();
  // build V^T: v16[k][row] = (row<8 ? r_root[row][k] : aggR[row-8][k])
  for (int idx = tid; idx < 16*HID; idx += 512) {
    int k = idx & 127, row = idx >> 7;
    float v = (row < 8) ? rl[(row*KR + KP)*132 + k] : aggR[row-8][k];
    v16[k*20 + row] = v;
  }
  __syncthreads();
  // H2 = V(16x128) @ Wg(128x128): thread = (row-quarter qr, col j), acc[4].
  {
    int qr = tid >> 7, j = tid & 127;
    float acc[4] = {0.f,0.f,0.f,0.f};
    const float* wgp = Wg + j;
    #pragma unroll 4
    for (int k = 0; k < HID; ++k) {
      float wv = wgp[(size_t)k*HID];
      float4 va = *(const float4*)&v16[k*20 + qr*4];
      acc[0] = fmaf(va.x, wv, acc[0]); acc[1] = fmaf(va.y, wv, acc[1]);
      acc[2] = fmaf(va.z, wv, acc[2]); acc[3] = fmaf(va.w, wv, acc[3]);
    }
    #pragma unroll
    for (int q = 0; q < 4; ++q) h2[qr*4 + q][j] = acc[q];
  }
  __syncthreads();
  // output: leaves elu(H2[m]); roots elu(H2[8+m]); 4 quarters x 34 rows
  {
    int j = tid & 127, qr = tid >> 7;
    float* out = rhat + (size_t)bt*NN*HID + j;
    for (int ni = 0; ni < 34; ++ni) {
      int n = qr*34 + ni;
      int m = n / KR, kk = n - m*KR;
      float v = (kk < KP) ? h2[m][j] : h2[8+m][j];
      v = (v > 0.f) ? v : (__expf(v) - 1.f);
      out[(size_t)n*HID] = v;
    }
  }
}

// ---------------------------------------------------------------------------
extern "C" void kernel_launch(void* const* d_in, const int* in_sizes, int n_in,
                              void* d_out, int out_size, void* d_ws, size_t ws_size,
                              hipStream_t stream) {
  (void)in_sizes; (void)n_in; (void)out_size; (void)ws_size;
  const float* feat  = (const float*)d_in[0];
  const float* W1    = (const float*)d_in[1];
  const float* b1    = (const float*)d_in[2];
  const float* W2    = (const float*)d_in[3];
  const float* b2    = (const float*)d_in[4];
  const float* W_ih  = (const float*)d_in[5];
  const float* W_hh  = (const float*)d_in[6];
  const float* b_ih  = (const float*)d_in[7];
  const float* b_hh  = (const float*)d_in[8];
  const float* Wg    = (const float*)d_in[9];
  const float* a_src = (const float*)d_in[10];
  const float* a_dst = (const float*)d_in[11];

  float* x    = (float*)d_ws;                       // (T, B*N, EMB) fp32 = 35.7 MB
  float* r    = (float*)d_out;                      // (B, T, N, HID)
  float* rhat = r + (size_t)BB*TB*NN*HID;           // (B, T, N, HID)

  k1_mlp<<<BB*TB, 256, 0, stream>>>(feat, W1, b1, W2, b2, x);
  k2_lstm<<<68, 512, 0, stream>>>(x, W_ih, W_hh, b_ih, b_hh, r);
  k3_gat<<<BB*TB, 512, 0, stream>>>(r, Wg, a_src, a_dst, rhat);
}